// Round 1
// 904.225 us; speedup vs baseline: 1.6024x; 1.6024x over previous
//
#include <hip/hip_runtime.h>
#include <stdint.h>

#define HW 3136
#define Wd 56
#define Cc 256
#define CH 64
#define Tt 8
#define Bb 8
#define NPART 13   // grid.x of k4 px-blocks (13*256px = 3328 >= 3136)

typedef unsigned short ushort_t;
typedef __attribute__((ext_vector_type(2))) unsigned short us2;
typedef __attribute__((ext_vector_type(4))) unsigned short us4;
typedef __attribute__((ext_vector_type(8))) unsigned short us8;
typedef __attribute__((ext_vector_type(8))) short short8;   // 8 bf16 (4 VGPRs) MFMA frag
typedef __attribute__((ext_vector_type(4))) float f4;
typedef __attribute__((ext_vector_type(2))) float f2;

__device__ __forceinline__ float bf2f(ushort_t u) {
    union { unsigned int i; float f; } v;
    v.i = ((unsigned int)u) << 16;
    return v.f;
}
__device__ __forceinline__ ushort_t f2bf(float f) {
    union { float f; unsigned int i; } v;
    v.f = f;
    unsigned int r = (v.i + 0x7FFFu + ((v.i >> 16) & 1u)) >> 16;
    return (ushort_t)r;
}

// ---------------- K0: pack w_reduce into MFMA B-fragments (bf16) ----------------
// wpack[ks=dt*8+cb][nt][lane][8]: col o = nt*16+(l&15), k = cb*32+(l>>4)*8+j
// grid 24, block 256 (nt = tid>>6, lane = tid&63)
__global__ __launch_bounds__(256) void k0_pack(const float* __restrict__ wr,
                                               ushort_t* __restrict__ wpack) {
    int ks = blockIdx.x;               // 0..23
    int dt = ks >> 3, cb = ks & 7;
    int nt = threadIdx.x >> 6, l = threadIdx.x & 63;
    int o = nt * 16 + (l & 15);
    int c0 = cb * 32 + (l >> 4) * 8;
    us8 v;
#pragma unroll
    for (int j = 0; j < 8; j++)
        v[j] = f2bf(wr[((long)o * Cc + c0 + j) * 3 + dt]);
    *(us8*)(wpack + (long)ks * 2048 + (nt * 64 + l) * 8) = v;
}

// ---------------- K1: channel max/mean pooling ----------------
__global__ __launch_bounds__(256) void k1_pool(const float* __restrict__ x,
                                               float* __restrict__ pooled) {
    int u = blockIdx.x * 256 + threadIdx.x;      // 50176 = 64 bt * 784 px4
    int px4 = u % 784, bt = u / 784;
    long base = (long)bt * Cc * HW + px4 * 4;
    float mx[4], sm[4];
#pragma unroll
    for (int j = 0; j < 4; j++) { mx[j] = -3.4e38f; sm[j] = 0.f; }
    for (int c = 0; c < Cc; c++) {
        f4 xv = *(const f4*)(x + base + (long)c * HW);
#pragma unroll
        for (int j = 0; j < 4; j++) {
            mx[j] = fmaxf(mx[j], xv[j]);
            sm[j] += xv[j];
        }
    }
    f4 pm, pa;
#pragma unroll
    for (int j = 0; j < 4; j++) { pm[j] = mx[j]; pa[j] = sm[j] * (1.f / 256.f); }
    *(f4*)(pooled + (long)bt * 2 * HW + px4 * 4) = pm;
    *(f4*)(pooled + (long)bt * 2 * HW + HW + px4 * 4) = pa;
}

// ---------------- K2: 7x7 2ch conv + sigmoid gate ----------------
__global__ __launch_bounds__(256) void k2_conv(const float* __restrict__ pooled,
                                               const float* __restrict__ wsp,
                                               float* __restrict__ gate) {
    __shared__ float img[2 * HW];
    __shared__ float wf[98];
    int bt = blockIdx.x, tid = threadIdx.x;
    const float* src = pooled + (long)bt * 2 * HW;
    for (int i = tid; i < 2 * HW; i += 256) img[i] = src[i];
    if (tid < 98) wf[tid] = wsp[tid];
    __syncthreads();
    for (int p = tid; p < HW; p += 256) {
        int y = p / Wd, xx = p % Wd;
        float acc = 0.f;
        for (int ci = 0; ci < 2; ci++)
            for (int ky = 0; ky < 7; ky++) {
                int yy = y + ky - 3;
                if (yy < 0 || yy >= Wd) continue;
                for (int kx = 0; kx < 7; kx++) {
                    int xc = xx + kx - 3;
                    if (xc < 0 || xc >= Wd) continue;
                    acc += wf[ci * 49 + ky * 7 + kx] * img[ci * HW + yy * Wd + xc];
                }
            }
        gate[(long)bt * HW + p] = 1.f + 1.f / (1.f + __expf(-acc));
    }
}

// ---------------- K2T: xs_T[bt][px][c] = bf16(x * gate), LDS-transposed ----------------
// grid (49 pxblk, 4 cblk, 64 bt), block 256. Tile 64c x 64px.
__global__ __launch_bounds__(256) void k2t(const float* __restrict__ x,
                                           const float* __restrict__ gate,
                                           ushort_t* __restrict__ xsT) {
    __shared__ __attribute__((aligned(16))) ushort_t lds[64 * 72];  // [px][c^swz], pad 72
    int tid = threadIdx.x;
    int pblk = blockIdx.x, cblk = blockIdx.y, bt = blockIdx.z;
    int p4 = tid & 15, crow = tid >> 4;   // crow 0..15
    f4 gv = *(const f4*)(gate + (long)bt * HW + pblk * 64 + p4 * 4);
    long xb = ((long)bt * Cc + cblk * 64 + crow) * HW + pblk * 64 + p4 * 4;
#pragma unroll
    for (int i = 0; i < 4; i++) {
        int c = i * 16 + crow;
        f4 xv = *(const f4*)(x + xb + (long)i * 16 * HW);
#pragma unroll
        for (int k = 0; k < 4; k++) {
            int p = p4 * 4 + k;
            lds[p * 72 + (c ^ (((p >> 3) & 7) * 8))] = f2bf(xv[k] * gv[k]);
        }
    }
    __syncthreads();
    long ob = ((long)bt * HW + pblk * 64) * 256 + cblk * 64;
    int c8 = tid & 7;
#pragma unroll
    for (int j = 0; j < 2; j++) {
        int p = j * 32 + (tid >> 3);
        short8 v = *(const short8*)(&lds[p * 72 + ((c8 * 8) ^ (((p >> 3) & 7) * 8))]);
        *(short8*)(xsT + ob + (long)p * 256 + c8 * 8) = v;
    }
}

// ---------------- K3M: MFMA temporal-reduce GEMM + BN + relu ----------------
// C[px, o] = sum_{c,dt} xsT[b, t+dt-1, px, c] * W[o][c][dt]
// grid (49, 64 bt), block (64,4): wave wv owns m-tile of 16 px, all 64 o (4 n-tiles).
__global__ __launch_bounds__(256) void k3m(
    const ushort_t* __restrict__ xsT, const ushort_t* __restrict__ wpack,
    const float* __restrict__ bng, const float* __restrict__ bnb,
    const float* __restrict__ bnm, const float* __restrict__ bnv,
    ushort_t* __restrict__ trelu) {
    int l = threadIdx.x;          // lane 0..63
    int wv = threadIdx.y;         // m-tile 0..3
    int bt = blockIdx.y, b = bt >> 3, t = bt & 7;
    int px0 = blockIdx.x * 64 + wv * 16;
    int lr = l & 15, lg = l >> 4;
    f4 acc[4] = {f4{0.f, 0.f, 0.f, 0.f}, f4{0.f, 0.f, 0.f, 0.f},
                 f4{0.f, 0.f, 0.f, 0.f}, f4{0.f, 0.f, 0.f, 0.f}};
#pragma unroll
    for (int dt = 0; dt < 3; dt++) {
        int tp = t + dt - 1;
        if (tp < 0 || tp >= Tt) continue;   // zero-pad: skip contribution
        // A-frag: lane holds row px = px0+lr, k = cb*32 + lg*8 + j (c-contiguous us8)
        const ushort_t* Ab = xsT + ((long)(b * Tt + tp) * HW + px0 + lr) * 256 + lg * 8;
        const ushort_t* Wb = wpack + (long)dt * 8 * 2048 + l * 8;
        for (int cb = 0; cb < 8; cb++) {
            short8 av = *(const short8*)(Ab + cb * 32);
            const ushort_t* wp = Wb + cb * 2048;
#pragma unroll
            for (int nt = 0; nt < 4; nt++) {
                short8 bv = *(const short8*)(wp + nt * 512);
                acc[nt] = __builtin_amdgcn_mfma_f32_16x16x32_bf16(av, bv, acc[nt], 0, 0, 0);
            }
        }
    }
    // epilogue: BN + relu + bf16. C layout: col o = nt*16+lr, row px = px0 + lg*4 + r
#pragma unroll
    for (int nt = 0; nt < 4; nt++) {
        int o = nt * 16 + lr;
        float inv = bng[o] * rsqrtf(bnv[o] + 1e-5f);
        float sh = bnb[o] - bnm[o] * inv;
        us4 st;
#pragma unroll
        for (int r = 0; r < 4; r++) {
            float v = acc[nt][r] * inv + sh;
            st[r] = f2bf(fmaxf(v, 0.f));
        }
        *(us4*)(trelu + ((long)(b * CH + o) * Tt + t) * HW + px0 + lg * 4) = st;
    }
}

// ---------------- K4: expand GEMM (64->256) + sigmoid + x_t + spatial-sum partials ----------------
__global__ __launch_bounds__(256) void k4_expand(
    const float* __restrict__ x, const float* __restrict__ gate,
    const ushort_t* __restrict__ trelu, const float* __restrict__ we,
    ushort_t* __restrict__ xt, float* __restrict__ vpart) {
    int tx = threadIdx.x, ty = threadIdx.y;
    int bt = blockIdx.y;
    int b = bt >> 3, t = bt & 7;
    int px = (blockIdx.x * 64 + tx) * 4;
    bool act = px < HW;
    int c0 = blockIdx.z * 16 + ty * 4;

    float acc[4][4];
#pragma unroll
    for (int ci = 0; ci < 4; ci++)
#pragma unroll
        for (int j = 0; j < 4; j++) acc[ci][j] = 0.f;

    if (act) {
        for (int o = 0; o < CH; o++) {
            us4 tvv = *(const us4*)(trelu + ((long)(b * CH + o) * Tt + t) * HW + px);
            float tf[4];
#pragma unroll
            for (int j = 0; j < 4; j++) tf[j] = bf2f(tvv[j]);
#pragma unroll
            for (int ci = 0; ci < 4; ci++) {
                float w = we[(long)(c0 + ci) * CH + o];
#pragma unroll
                for (int j = 0; j < 4; j++) acc[ci][j] += w * tf[j];
            }
        }
    }

    float gg[4];
#pragma unroll
    for (int j = 0; j < 4; j++) gg[j] = 0.f;
    if (act) {
        f4 gv = *(const f4*)(gate + (long)bt * HW + px);
#pragma unroll
        for (int j = 0; j < 4; j++) gg[j] = gv[j];
    }

    float csum[4];
#pragma unroll
    for (int ci = 0; ci < 4; ci++) {
        float s = 0.f;
        if (act) {
            int c = c0 + ci;
            f4 xv = *(const f4*)(x + ((long)bt * Cc + c) * HW + px);
            us4 st;
#pragma unroll
            for (int j = 0; j < 4; j++) {
                float attn = 1.f / (1.f + __expf(-acc[ci][j]));
                float v = xv[j] * gg[j] * (1.f + attn);
                st[j] = f2bf(v);
                s += v;
            }
            *(us4*)(xt + ((long)(b * Cc + c) * Tt + t) * HW + px) = st;
        }
        csum[ci] = s;
    }

#pragma unroll
    for (int ci = 0; ci < 4; ci++) {
        float s = csum[ci];
        for (int off = 32; off > 0; off >>= 1) s += __shfl_down(s, off);
        if (tx == 0)
            vpart[((long)(b * Cc + (c0 + ci)) * Tt + t) * NPART + blockIdx.x] = s;
    }
}

// ---------------- K5: dynamic temporal kernel (fc1->relu->fc2->softmax) ----------------
__global__ __launch_bounds__(256) void k5_dyn(
    const float* __restrict__ vpart, const float* __restrict__ wfc1,
    const float* __restrict__ bfc1, const float* __restrict__ wfc2,
    const float* __restrict__ bfc2, float* __restrict__ dk) {
    int u = blockIdx.x * 256 + threadIdx.x;   // 2048 = B*C
    int b = u >> 8, c = u & 255;
    float v[8];
#pragma unroll
    for (int t = 0; t < 8; t++) {
        float s = 0.f;
        for (int i = 0; i < NPART; i++)
            s += vpart[((long)(b * Cc + c) * Tt + t) * NPART + i];
        v[t] = s * (1.f / 3136.f);
    }
    float h[16];
#pragma unroll
    for (int j = 0; j < 16; j++) {
        float s = bfc1[j];
        for (int t = 0; t < 8; t++) s += wfc1[j * 8 + t] * v[t];
        h[j] = fmaxf(s, 0.f);
    }
    float l[3];
#pragma unroll
    for (int k = 0; k < 3; k++) {
        float s = bfc2[k];
        for (int j = 0; j < 16; j++) s += wfc2[k * 16 + j] * h[j];
        l[k] = s;
    }
    float m = fmaxf(l[0], fmaxf(l[1], l[2]));
    float e0 = __expf(l[0] - m), e1 = __expf(l[1] - m), e2 = __expf(l[2] - m);
    float inv = 1.f / (e0 + e1 + e2);
    dk[(long)u * 3 + 0] = e0 * inv;
    dk[(long)u * 3 + 1] = e1 * inv;
    dk[(long)u * 3 + 2] = e2 * inv;
}

// ---------------- K6: depthwise temporal 3-tap stencil ----------------
__global__ __launch_bounds__(256) void k6_stencil(
    const ushort_t* __restrict__ xt, const float* __restrict__ dk,
    float* __restrict__ out) {
    int tx = threadIdx.x;
    int c = blockIdx.y, b = blockIdx.z;
    int px = (blockIdx.x * 256 + tx) * 2;
    if (px >= HW) return;
    const float* kk = dk + (long)(b * Cc + c) * 3;
    float k0 = kk[0], k1 = kk[1], k2 = kk[2];
    float pa[Tt][2];
    const ushort_t* src = xt + (long)(b * Cc + c) * Tt * HW + px;
#pragma unroll
    for (int t = 0; t < Tt; t++) {
        us2 xv = *(const us2*)(src + (long)t * HW);
        pa[t][0] = bf2f(xv[0]);
        pa[t][1] = bf2f(xv[1]);
    }
#pragma unroll
    for (int t = 0; t < Tt; t++) {
        float am = (t > 0) ? pa[t - 1][0] : 0.f, bm = (t > 0) ? pa[t - 1][1] : 0.f;
        float ap = (t < 7) ? pa[t + 1][0] : 0.f, bp = (t < 7) ? pa[t + 1][1] : 0.f;
        f2 r;
        r[0] = k0 * am + k1 * pa[t][0] + k2 * ap;
        r[1] = k0 * bm + k1 * pa[t][1] + k2 * bp;
        *(f2*)(out + ((long)(b * Tt + t) * Cc + c) * HW + px) = r;
    }
}

extern "C" void kernel_launch(void* const* d_in, const int* in_sizes, int n_in,
                              void* d_out, int out_size, void* d_ws, size_t ws_size,
                              hipStream_t stream) {
    const float* x    = (const float*)d_in[0];
    const float* wsp  = (const float*)d_in[1];
    const float* wr   = (const float*)d_in[2];
    const float* bng  = (const float*)d_in[3];
    const float* bnb  = (const float*)d_in[4];
    const float* bnm  = (const float*)d_in[5];
    const float* bnv  = (const float*)d_in[6];
    const float* we   = (const float*)d_in[7];
    const float* wfc1 = (const float*)d_in[8];
    const float* bfc1 = (const float*)d_in[9];
    const float* wfc2 = (const float*)d_in[10];
    const float* bfc2 = (const float*)d_in[11];
    float* out = (float*)d_out;

    char* ws = (char*)d_ws;
    size_t off = 0;
    float* pooled = (float*)(ws + off); off += (size_t)64 * 2 * HW * 4;            // 1.6 MB
    float* gate   = (float*)(ws + off); off += (size_t)64 * HW * 4;                // 0.8 MB
    ushort_t* trelu = (ushort_t*)(ws + off); off += (size_t)Bb * CH * Tt * HW * 2; // 25.7 MB
    // xs_T[bt][px][c] bf16 (102.8 MB) — aliased with xt (same size): k3m consumes
    // xs_T fully before k4 writes xt (sequential stream).
    ushort_t* xsT = (ushort_t*)(ws + off); off += (size_t)Bb * Tt * HW * Cc * 2;   // 102.8 MB
    ushort_t* xt = xsT;
    float* vpart  = (float*)(ws + off); off += (size_t)Bb * Cc * Tt * NPART * 4;   // 0.9 MB
    float* dk     = (float*)(ws + off); off += (size_t)Bb * Cc * 3 * 4;            // 24 KB
    ushort_t* wpack = (ushort_t*)(ws + off); off += (size_t)24 * 2048 * 2;         // 96 KB

    hipLaunchKernelGGL(k0_pack, dim3(24), dim3(256), 0, stream, wr, wpack);
    hipLaunchKernelGGL(k1_pool, dim3(196), dim3(256), 0, stream, x, pooled);
    hipLaunchKernelGGL(k2_conv, dim3(64), dim3(256), 0, stream, pooled, wsp, gate);
    hipLaunchKernelGGL(k2t, dim3(49, 4, 64), dim3(256), 0, stream, x, gate, xsT);
    hipLaunchKernelGGL(k3m, dim3(49, 64), dim3(64, 4), 0, stream,
                       xsT, wpack, bng, bnb, bnm, bnv, trelu);
    hipLaunchKernelGGL(k4_expand, dim3(NPART, 64, 16), dim3(64, 4), 0, stream,
                       x, gate, trelu, we, xt, vpart);
    hipLaunchKernelGGL(k5_dyn, dim3(8), dim3(256), 0, stream,
                       vpart, wfc1, bfc1, wfc2, bfc2, dk);
    hipLaunchKernelGGL(k6_stencil, dim3(7, 256, 8), dim3(256), 0, stream, xt, dk, out);
}

// Round 2
// 716.383 us; speedup vs baseline: 2.0226x; 1.2622x over previous
//
#include <hip/hip_runtime.h>
#include <stdint.h>

#define HW 3136
#define Wd 56
#define Cc 256
#define CH 64
#define Tt 8
#define Bb 8
#define VP 49   // spatial-sum partials per (b,c,t): one per 64-px block

typedef unsigned short ushort_t;
typedef __attribute__((ext_vector_type(2))) unsigned short us2;
typedef __attribute__((ext_vector_type(4))) unsigned short us4;
typedef __attribute__((ext_vector_type(8))) unsigned short us8;
typedef __attribute__((ext_vector_type(8))) short short8;   // 8 bf16 (4 VGPRs) MFMA frag
typedef __attribute__((ext_vector_type(4))) float f4;
typedef __attribute__((ext_vector_type(2))) float f2;

__device__ __forceinline__ float bf2f(ushort_t u) {
    union { unsigned int i; float f; } v;
    v.i = ((unsigned int)u) << 16;
    return v.f;
}
__device__ __forceinline__ ushort_t f2bf(float f) {
    union { float f; unsigned int i; } v;
    v.f = f;
    unsigned int r = (v.i + 0x7FFFu + ((v.i >> 16) & 1u)) >> 16;
    return (ushort_t)r;
}

// ---------------- K0: pack weights into MFMA fragments (bf16) ----------------
// bx<24:  wpack[ks=dt*8+cb][mt][lane][8]: o = mt*16+(l&15), k(c) = cb*32+(l>>4)*8+j,
//         pre-scaled by BN inv[o]. Also shb[o] = bnb - bnm*inv (acc-init bias).
// bx>=24: wepack[kb][ntg][lane][8]: c = ntg*16+(l&15), k(o) = kb*32+(l>>4)*8+j.
__global__ __launch_bounds__(256) void k0_pack(
    const float* __restrict__ wr, const float* __restrict__ bng,
    const float* __restrict__ bnb, const float* __restrict__ bnm,
    const float* __restrict__ bnv, const float* __restrict__ we,
    ushort_t* __restrict__ wpack, ushort_t* __restrict__ wepack,
    float* __restrict__ shb) {
    int bx = blockIdx.x, tid = threadIdx.x;
    if (bx < 24) {
        int dt = bx >> 3, cb = bx & 7;
        int mt = tid >> 6, l = tid & 63;
        int o = mt * 16 + (l & 15);
        float inv = bng[o] * rsqrtf(bnv[o] + 1e-5f);
        int c0 = cb * 32 + (l >> 4) * 8;
        us8 v;
#pragma unroll
        for (int j = 0; j < 8; j++)
            v[j] = f2bf(wr[((long)o * Cc + c0 + j) * 3 + dt] * inv);
        *(us8*)(wpack + (long)bx * 2048 + (mt * 64 + l) * 8) = v;
        if (bx == 0 && tid < CH)
            shb[tid] = bnb[tid] - bnm[tid] * (bng[tid] * rsqrtf(bnv[tid] + 1e-5f));
    } else {
        int u = (bx - 24) * 256 + tid;          // 0..2047
        int l = u & 63;
        int c = ((u >> 6) & 15) * 16 + (l & 15);
        int o0 = (u >> 10) * 32 + (l >> 4) * 8;
        us8 v;
#pragma unroll
        for (int j = 0; j < 8; j++)
            v[j] = f2bf(we[(long)c * CH + o0 + j]);
        *(us8*)(wepack + (long)u * 8) = v;
    }
}

// ---------------- K1: channel max/mean pooling ----------------
__global__ __launch_bounds__(256) void k1_pool(const float* __restrict__ x,
                                               float* __restrict__ pooled) {
    int u = blockIdx.x * 256 + threadIdx.x;      // 50176 = 64 bt * 784 px4
    int px4 = u % 784, bt = u / 784;
    long base = (long)bt * Cc * HW + px4 * 4;
    float mx[4], sm[4];
#pragma unroll
    for (int j = 0; j < 4; j++) { mx[j] = -3.4e38f; sm[j] = 0.f; }
    for (int c = 0; c < Cc; c++) {
        f4 xv = *(const f4*)(x + base + (long)c * HW);
#pragma unroll
        for (int j = 0; j < 4; j++) {
            mx[j] = fmaxf(mx[j], xv[j]);
            sm[j] += xv[j];
        }
    }
    f4 pm, pa;
#pragma unroll
    for (int j = 0; j < 4; j++) { pm[j] = mx[j]; pa[j] = sm[j] * (1.f / 256.f); }
    *(f4*)(pooled + (long)bt * 2 * HW + px4 * 4) = pm;
    *(f4*)(pooled + (long)bt * 2 * HW + HW + px4 * 4) = pa;
}

// ---------------- K2: 7x7 2ch conv + sigmoid gate ----------------
__global__ __launch_bounds__(256) void k2_conv(const float* __restrict__ pooled,
                                               const float* __restrict__ wsp,
                                               float* __restrict__ gate) {
    __shared__ float img[2 * HW];
    __shared__ float wf[98];
    int bt = blockIdx.x, tid = threadIdx.x;
    const float* src = pooled + (long)bt * 2 * HW;
    for (int i = tid; i < 2 * HW; i += 256) img[i] = src[i];
    if (tid < 98) wf[tid] = wsp[tid];
    __syncthreads();
    for (int p = tid; p < HW; p += 256) {
        int y = p / Wd, xx = p % Wd;
        float acc = 0.f;
        for (int ci = 0; ci < 2; ci++)
            for (int ky = 0; ky < 7; ky++) {
                int yy = y + ky - 3;
                if (yy < 0 || yy >= Wd) continue;
                for (int kx = 0; kx < 7; kx++) {
                    int xc = xx + kx - 3;
                    if (xc < 0 || xc >= Wd) continue;
                    acc += wf[ci * 49 + ky * 7 + kx] * img[ci * HW + yy * Wd + xc];
                }
            }
        gate[(long)bt * HW + p] = 1.f + 1.f / (1.f + __expf(-acc));
    }
}

// ---------------- K2T: xs_T[bt][px][c] = bf16(x * gate), LDS-transposed ----------------
// grid (49 pxblk, 4 cblk, 64 bt), block 256. Tile 64c x 64px.
__global__ __launch_bounds__(256) void k2t(const float* __restrict__ x,
                                           const float* __restrict__ gate,
                                           ushort_t* __restrict__ xsT) {
    __shared__ __attribute__((aligned(16))) ushort_t lds[64 * 72];  // [px][c^swz], pad 72
    int tid = threadIdx.x;
    int pblk = blockIdx.x, cblk = blockIdx.y, bt = blockIdx.z;
    int p4 = tid & 15, crow = tid >> 4;   // crow 0..15
    f4 gv = *(const f4*)(gate + (long)bt * HW + pblk * 64 + p4 * 4);
    long xb = ((long)bt * Cc + cblk * 64 + crow) * HW + pblk * 64 + p4 * 4;
#pragma unroll
    for (int i = 0; i < 4; i++) {
        int c = i * 16 + crow;
        f4 xv = *(const f4*)(x + xb + (long)i * 16 * HW);
#pragma unroll
        for (int k = 0; k < 4; k++) {
            int p = p4 * 4 + k;
            lds[p * 72 + (c ^ (((p >> 3) & 7) * 8))] = f2bf(xv[k] * gv[k]);
        }
    }
    __syncthreads();
    long ob = ((long)bt * HW + pblk * 64) * 256 + cblk * 64;
    int c8 = tid & 7;
#pragma unroll
    for (int j = 0; j < 2; j++) {
        int p = j * 32 + (tid >> 3);
        short8 v = *(const short8*)(&lds[p * 72 + ((c8 * 8) ^ (((p >> 3) & 7) * 8))]);
        *(short8*)(xsT + ob + (long)p * 256 + c8 * 8) = v;
    }
}

// ---------------- K3M: MFMA temporal-reduce GEMM (BN folded) + relu ----------------
// C[o, px] = sum_{c,dt} W'[o][c][dt] * xsT[b, t+dt-1, px, c]  (A = W', B = X)
// C layout: col(N=px) = l&15, row(M=o) = (l>>4)*4+r  -> lane holds 4 consecutive o
// trelu stored as [bt][px][o] (o contiguous).
// grid (49, 64 bt), block (64,4): wave wv owns 16 px, all 64 o (4 m-tiles).
__global__ __launch_bounds__(256) void k3m(
    const ushort_t* __restrict__ xsT, const ushort_t* __restrict__ wpack,
    const float* __restrict__ shb, ushort_t* __restrict__ trelu) {
    int l = threadIdx.x;          // lane 0..63
    int wv = threadIdx.y;         // px sub-tile 0..3
    int bt = blockIdx.y, b = bt >> 3, t = bt & 7;
    int px0 = blockIdx.x * 64 + wv * 16;
    int lr = l & 15, lg = l >> 4;
    f4 acc[4];
#pragma unroll
    for (int mt = 0; mt < 4; mt++)   // acc init = BN shift for o = mt*16+lg*4+r
        acc[mt] = *(const f4*)(shb + mt * 16 + lg * 4);
#pragma unroll
    for (int dt = 0; dt < 3; dt++) {
        int tp = t + dt - 1;
        if (tp < 0 || tp >= Tt) continue;   // zero-pad: skip contribution
        // B-frag: lane holds col px = px0+lr, k = cb*32 + lg*8 + j (c-contiguous us8)
        const ushort_t* Bp = xsT + ((long)(b * Tt + tp) * HW + px0 + lr) * 256 + lg * 8;
        const ushort_t* Ap = wpack + (long)dt * 8 * 2048 + l * 8;
        for (int cb = 0; cb < 8; cb++) {
            short8 bv = *(const short8*)(Bp + cb * 32);
            const ushort_t* ap = Ap + cb * 2048;
#pragma unroll
            for (int mt = 0; mt < 4; mt++) {
                short8 av = *(const short8*)(ap + mt * 512);
                acc[mt] = __builtin_amdgcn_mfma_f32_16x16x32_bf16(av, bv, acc[mt], 0, 0, 0);
            }
        }
    }
    // epilogue: relu + bf16; store [px][o], us4 over 4 consecutive o
#pragma unroll
    for (int mt = 0; mt < 4; mt++) {
        us4 st;
#pragma unroll
        for (int r = 0; r < 4; r++)
            st[r] = f2bf(fmaxf(acc[mt][r], 0.f));
        *(us4*)(trelu + ((long)bt * HW + px0 + lr) * 64 + mt * 16 + lg * 4) = st;
    }
}

// ---------------- K4M: MFMA expand GEMM + sigmoid + x_t + spatial-sum partials ----------------
// C[px, c] = sum_o trelu[bt][px][o] * we[c][o]   (A = trelu, B = wepack)
// C layout: col(N=c) = l&15, row(M=px) = (l>>4)*4+r -> lane holds 4 consecutive px
// grid (49, 64 bt, 2 c-halves), block (64,4): wave wv owns 64 px x 32 c (2 n-tiles).
__global__ __launch_bounds__(256) void k4m(
    const float* __restrict__ x, const float* __restrict__ gate,
    const ushort_t* __restrict__ trelu, const ushort_t* __restrict__ wepack,
    ushort_t* __restrict__ xt, float* __restrict__ vpart) {
    int l = threadIdx.x, wv = threadIdx.y;
    int bt = blockIdx.y, b = bt >> 3, t = bt & 7;
    int P0 = blockIdx.x * 64;
    int lr = l & 15, lg = l >> 4;
    int ntg0 = blockIdx.z * 8 + wv * 2;       // global c-tile base (2 tiles per wave)

    short8 bfr[2][2];                          // [kb][ni] held in regs
#pragma unroll
    for (int kb = 0; kb < 2; kb++)
#pragma unroll
        for (int ni = 0; ni < 2; ni++)
            bfr[kb][ni] = *(const short8*)(wepack + ((long)(kb * 16 + ntg0 + ni) * 64 + l) * 8);

    f4 acc[4][2];
#pragma unroll
    for (int mi = 0; mi < 4; mi++)
#pragma unroll
        for (int ni = 0; ni < 2; ni++) acc[mi][ni] = f4{0.f, 0.f, 0.f, 0.f};

    const ushort_t* Ab = trelu + ((long)bt * HW + P0 + lr) * 64;
#pragma unroll
    for (int mi = 0; mi < 4; mi++) {
#pragma unroll
        for (int kb = 0; kb < 2; kb++) {
            short8 av = *(const short8*)(Ab + (long)mi * 16 * 64 + kb * 32 + lg * 8);
#pragma unroll
            for (int ni = 0; ni < 2; ni++)
                acc[mi][ni] = __builtin_amdgcn_mfma_f32_16x16x32_bf16(av, bfr[kb][ni],
                                                                      acc[mi][ni], 0, 0, 0);
        }
    }

    float csum[2] = {0.f, 0.f};
#pragma unroll
    for (int mi = 0; mi < 4; mi++) {
        int pxb = P0 + mi * 16 + lg * 4;
        f4 gv = *(const f4*)(gate + (long)bt * HW + pxb);
#pragma unroll
        for (int ni = 0; ni < 2; ni++) {
            int c = (ntg0 + ni) * 16 + lr;
            f4 xv = *(const f4*)(x + ((long)bt * Cc + c) * HW + pxb);
            us4 st;
            float s = 0.f;
#pragma unroll
            for (int r = 0; r < 4; r++) {
                float attn = 1.f / (1.f + __expf(-acc[mi][ni][r]));
                float v = xv[r] * gv[r] * (1.f + attn);
                st[r] = f2bf(v);
                s += v;
            }
            *(us4*)(xt + ((long)(b * Cc + c) * Tt + t) * HW + pxb) = st;
            csum[ni] += s;
        }
    }

    // reduce over lg (lanes l, l+16, l+32, l+48 share the same c)
#pragma unroll
    for (int ni = 0; ni < 2; ni++) {
        float s = csum[ni];
        s += __shfl_xor(s, 16);
        s += __shfl_xor(s, 32);
        if (lg == 0) {
            int c = (ntg0 + ni) * 16 + lr;
            vpart[((long)(b * Cc + c) * Tt + t) * VP + blockIdx.x] = s;
        }
    }
}

// ---------------- K5: dynamic temporal kernel (fc1->relu->fc2->softmax) ----------------
__global__ __launch_bounds__(256) void k5_dyn(
    const float* __restrict__ vpart, const float* __restrict__ wfc1,
    const float* __restrict__ bfc1, const float* __restrict__ wfc2,
    const float* __restrict__ bfc2, float* __restrict__ dk) {
    int u = blockIdx.x * 256 + threadIdx.x;   // 2048 = B*C
    int b = u >> 8, c = u & 255;
    float v[8];
#pragma unroll
    for (int t = 0; t < 8; t++) {
        float s = 0.f;
        for (int i = 0; i < VP; i++)
            s += vpart[((long)(b * Cc + c) * Tt + t) * VP + i];
        v[t] = s * (1.f / 3136.f);
    }
    float h[16];
#pragma unroll
    for (int j = 0; j < 16; j++) {
        float s = bfc1[j];
        for (int t = 0; t < 8; t++) s += wfc1[j * 8 + t] * v[t];
        h[j] = fmaxf(s, 0.f);
    }
    float l[3];
#pragma unroll
    for (int k = 0; k < 3; k++) {
        float s = bfc2[k];
        for (int j = 0; j < 16; j++) s += wfc2[k * 16 + j] * h[j];
        l[k] = s;
    }
    float m = fmaxf(l[0], fmaxf(l[1], l[2]));
    float e0 = __expf(l[0] - m), e1 = __expf(l[1] - m), e2 = __expf(l[2] - m);
    float inv = 1.f / (e0 + e1 + e2);
    dk[(long)u * 3 + 0] = e0 * inv;
    dk[(long)u * 3 + 1] = e1 * inv;
    dk[(long)u * 3 + 2] = e2 * inv;
}

// ---------------- K6: depthwise temporal 3-tap stencil ----------------
__global__ __launch_bounds__(256) void k6_stencil(
    const ushort_t* __restrict__ xt, const float* __restrict__ dk,
    float* __restrict__ out) {
    int tx = threadIdx.x;
    int c = blockIdx.y, b = blockIdx.z;
    int px = (blockIdx.x * 256 + tx) * 2;
    if (px >= HW) return;
    const float* kk = dk + (long)(b * Cc + c) * 3;
    float k0 = kk[0], k1 = kk[1], k2 = kk[2];
    float pa[Tt][2];
    const ushort_t* src = xt + (long)(b * Cc + c) * Tt * HW + px;
#pragma unroll
    for (int t = 0; t < Tt; t++) {
        us2 xv = *(const us2*)(src + (long)t * HW);
        pa[t][0] = bf2f(xv[0]);
        pa[t][1] = bf2f(xv[1]);
    }
#pragma unroll
    for (int t = 0; t < Tt; t++) {
        float am = (t > 0) ? pa[t - 1][0] : 0.f, bm = (t > 0) ? pa[t - 1][1] : 0.f;
        float ap = (t < 7) ? pa[t + 1][0] : 0.f, bp = (t < 7) ? pa[t + 1][1] : 0.f;
        f2 r;
        r[0] = k0 * am + k1 * pa[t][0] + k2 * ap;
        r[1] = k0 * bm + k1 * pa[t][1] + k2 * bp;
        *(f2*)(out + ((long)(b * Tt + t) * Cc + c) * HW + px) = r;
    }
}

extern "C" void kernel_launch(void* const* d_in, const int* in_sizes, int n_in,
                              void* d_out, int out_size, void* d_ws, size_t ws_size,
                              hipStream_t stream) {
    const float* x    = (const float*)d_in[0];
    const float* wsp  = (const float*)d_in[1];
    const float* wr   = (const float*)d_in[2];
    const float* bng  = (const float*)d_in[3];
    const float* bnb  = (const float*)d_in[4];
    const float* bnm  = (const float*)d_in[5];
    const float* bnv  = (const float*)d_in[6];
    const float* we   = (const float*)d_in[7];
    const float* wfc1 = (const float*)d_in[8];
    const float* bfc1 = (const float*)d_in[9];
    const float* wfc2 = (const float*)d_in[10];
    const float* bfc2 = (const float*)d_in[11];
    float* out = (float*)d_out;

    char* ws = (char*)d_ws;
    size_t off = 0;
    float* pooled = (float*)(ws + off); off += (size_t)64 * 2 * HW * 4;            // 1.6 MB
    float* gate   = (float*)(ws + off); off += (size_t)64 * HW * 4;                // 0.8 MB
    ushort_t* trelu = (ushort_t*)(ws + off); off += (size_t)Bb * CH * Tt * HW * 2; // 25.7 MB
    // xs_T[bt][px][c] bf16 (102.8 MB) — aliased with xt (same size): k3m consumes
    // xs_T fully before k4m writes xt (sequential stream).
    ushort_t* xsT = (ushort_t*)(ws + off); off += (size_t)Bb * Tt * HW * Cc * 2;   // 102.8 MB
    ushort_t* xt = xsT;
    float* vpart  = (float*)(ws + off); off += (size_t)Bb * Cc * Tt * VP * 4;      // 3.2 MB
    float* dk     = (float*)(ws + off); off += (size_t)Bb * Cc * 3 * 4;            // 24 KB
    ushort_t* wpack = (ushort_t*)(ws + off); off += (size_t)24 * 2048 * 2;         // 96 KB
    ushort_t* wepack = (ushort_t*)(ws + off); off += (size_t)2048 * 8 * 2;         // 32 KB
    float* shb    = (float*)(ws + off); off += (size_t)CH * 4;                     // 256 B

    hipLaunchKernelGGL(k0_pack, dim3(32), dim3(256), 0, stream,
                       wr, bng, bnb, bnm, bnv, we, wpack, wepack, shb);
    hipLaunchKernelGGL(k1_pool, dim3(196), dim3(256), 0, stream, x, pooled);
    hipLaunchKernelGGL(k2_conv, dim3(64), dim3(256), 0, stream, pooled, wsp, gate);
    hipLaunchKernelGGL(k2t, dim3(49, 4, 64), dim3(256), 0, stream, x, gate, xsT);
    hipLaunchKernelGGL(k3m, dim3(49, 64), dim3(64, 4), 0, stream,
                       xsT, wpack, shb, trelu);
    hipLaunchKernelGGL(k4m, dim3(49, 64, 2), dim3(64, 4), 0, stream,
                       x, gate, trelu, wepack, xt, vpart);
    hipLaunchKernelGGL(k5_dyn, dim3(8), dim3(256), 0, stream,
                       vpart, wfc1, bfc1, wfc2, bfc2, dk);
    hipLaunchKernelGGL(k6_stencil, dim3(7, 256, 8), dim3(256), 0, stream, xt, dk, out);
}

// Round 3
// 663.116 us; speedup vs baseline: 2.1851x; 1.0803x over previous
//
#include <hip/hip_runtime.h>
#include <stdint.h>

#define HW 3136
#define Wd 56
#define Cc 256
#define CH 64
#define Tt 8
#define Bb 8
#define VP 49   // spatial-sum partials per (b,c,t): one per 64-px block of k4m

typedef unsigned short ushort_t;
typedef __attribute__((ext_vector_type(2))) unsigned short us2;
typedef __attribute__((ext_vector_type(4))) unsigned short us4;
typedef __attribute__((ext_vector_type(8))) unsigned short us8;
typedef __attribute__((ext_vector_type(8))) short short8;   // 8 bf16 (4 VGPRs) MFMA frag
typedef __attribute__((ext_vector_type(4))) float f4;
typedef __attribute__((ext_vector_type(2))) float f2;

__device__ __forceinline__ float bf2f(ushort_t u) {
    union { unsigned int i; float f; } v;
    v.i = ((unsigned int)u) << 16;
    return v.f;
}
__device__ __forceinline__ ushort_t f2bf(float f) {
    union { float f; unsigned int i; } v;
    v.f = f;
    unsigned int r = (v.i + 0x7FFFu + ((v.i >> 16) & 1u)) >> 16;
    return (ushort_t)r;
}

// ---------------- K0: pack weights into MFMA fragments (bf16) ----------------
// bx<24:  wpack[ks=dt*8+cb][mt][lane][8]: o = mt*16+(l&15), k(c) = cb*32+(l>>4)*8+j,
//         pre-scaled by BN inv[o]. Also shb[o] = bnb - bnm*inv (acc-init bias).
// bx>=24: wepack[kb][ntg][lane][8]: c = ntg*16+(l&15), k(o) = kb*32+(l>>4)*8+j.
__global__ __launch_bounds__(256) void k0_pack(
    const float* __restrict__ wr, const float* __restrict__ bng,
    const float* __restrict__ bnb, const float* __restrict__ bnm,
    const float* __restrict__ bnv, const float* __restrict__ we,
    ushort_t* __restrict__ wpack, ushort_t* __restrict__ wepack,
    float* __restrict__ shb) {
    int bx = blockIdx.x, tid = threadIdx.x;
    if (bx < 24) {
        int dt = bx >> 3, cb = bx & 7;
        int mt = tid >> 6, l = tid & 63;
        int o = mt * 16 + (l & 15);
        float inv = bng[o] * rsqrtf(bnv[o] + 1e-5f);
        int c0 = cb * 32 + (l >> 4) * 8;
        us8 v;
#pragma unroll
        for (int j = 0; j < 8; j++)
            v[j] = f2bf(wr[((long)o * Cc + c0 + j) * 3 + dt] * inv);
        *(us8*)(wpack + (long)bx * 2048 + (mt * 64 + l) * 8) = v;
        if (bx == 0 && tid < CH)
            shb[tid] = bnb[tid] - bnm[tid] * (bng[tid] * rsqrtf(bnv[tid] + 1e-5f));
    } else {
        int u = (bx - 24) * 256 + tid;          // 0..2047
        int l = u & 63;
        int c = ((u >> 6) & 15) * 16 + (l & 15);
        int o0 = (u >> 10) * 32 + (l >> 4) * 8;
        us8 v;
#pragma unroll
        for (int j = 0; j < 8; j++)
            v[j] = f2bf(we[(long)c * CH + o0 + j]);
        *(us8*)(wepack + (long)u * 8) = v;
    }
}

// ---------------- K1: channel max/mean pooling, 4-way c-split ----------------
// grid (196, 4), block 256. part q covers c in [q*64, q*64+64); partials combined in k2.
__global__ __launch_bounds__(256) void k1_pool(const float* __restrict__ x,
                                               float* __restrict__ pooledp) {
    int u = blockIdx.x * 256 + threadIdx.x;      // 50176 = 64 bt * 784 px4
    int q = blockIdx.y;
    int px4 = u % 784, bt = u / 784;
    long base = ((long)bt * Cc + (long)q * 64) * HW + px4 * 4;
    float mx[4], sm[4];
#pragma unroll
    for (int j = 0; j < 4; j++) { mx[j] = -3.4e38f; sm[j] = 0.f; }
    for (int c = 0; c < 64; c++) {
        f4 xv = *(const f4*)(x + base + (long)c * HW);
#pragma unroll
        for (int j = 0; j < 4; j++) {
            mx[j] = fmaxf(mx[j], xv[j]);
            sm[j] += xv[j];
        }
    }
    f4 pm, ps;
#pragma unroll
    for (int j = 0; j < 4; j++) { pm[j] = mx[j]; ps[j] = sm[j]; }
    *(f4*)(pooledp + ((long)(q * 64 + bt) * 2 + 0) * HW + px4 * 4) = pm;
    *(f4*)(pooledp + ((long)(q * 64 + bt) * 2 + 1) * HW + px4 * 4) = ps;
}

// ---------------- K2: combine partials + 7x7 2ch conv + sigmoid gate ----------------
__global__ __launch_bounds__(256) void k2_conv(const float* __restrict__ pooledp,
                                               const float* __restrict__ wsp,
                                               float* __restrict__ gate) {
    __shared__ float img[2 * HW];
    __shared__ float wf[98];
    int bt = blockIdx.x, tid = threadIdx.x;
    for (int i = tid; i < HW; i += 256) {
        float m = -3.4e38f, s = 0.f;
#pragma unroll
        for (int q = 0; q < 4; q++) {
            const float* pq = pooledp + (long)(q * 64 + bt) * 2 * HW;
            m = fmaxf(m, pq[i]);
            s += pq[HW + i];
        }
        img[i] = m;
        img[HW + i] = s * (1.f / 256.f);
    }
    if (tid < 98) wf[tid] = wsp[tid];
    __syncthreads();
    for (int p = tid; p < HW; p += 256) {
        int y = p / Wd, xx = p % Wd;
        float acc = 0.f;
        for (int ci = 0; ci < 2; ci++)
            for (int ky = 0; ky < 7; ky++) {
                int yy = y + ky - 3;
                if (yy < 0 || yy >= Wd) continue;
                for (int kx = 0; kx < 7; kx++) {
                    int xc = xx + kx - 3;
                    if (xc < 0 || xc >= Wd) continue;
                    acc += wf[ci * 49 + ky * 7 + kx] * img[ci * HW + yy * Wd + xc];
                }
            }
        gate[(long)bt * HW + p] = 1.f + 1.f / (1.f + __expf(-acc));
    }
}

// ---------------- K23: fused gate-apply + LDS transpose + temporal-reduce MFMA GEMM ----------------
// Per (b, 32-px tile): stage bf16(x*gate) for all 8 t x 64c chunk into LDS (transposed,
// XOR-swizzled), then each wave (= one t) accumulates C[o,px] over 3 taps via MFMA.
// trelu[bt][px][o] o-contiguous, BN folded (weights pre-scaled, bias in acc init) + relu.
// grid (98, 8 b), block 512 (8 waves), dynamic LDS 37888 B.
__global__ __launch_bounds__(512) void k23_fused(
    const float* __restrict__ x, const float* __restrict__ gate,
    const ushort_t* __restrict__ wpack, const float* __restrict__ shb,
    ushort_t* __restrict__ trelu) {
    extern __shared__ char smem[];
    ushort_t* xs = (ushort_t*)smem;                 // [8t*32px rows][72]
    float* gl = (float*)(smem + 256 * 72 * 2);      // [8t][32px]
    int tid = threadIdx.x;
    int px0 = blockIdx.x * 32, b = blockIdx.y;
    // stage gate tile
    if (tid < 256) {
        int tg = tid >> 5, pg = tid & 31;
        gl[tid] = gate[(long)(b * 8 + tg) * HW + px0 + pg];
    }
    int t = tid >> 6;            // wave id = output t
    int l = tid & 63;
    int lr = l & 15, lg = l >> 4;
    int cst = tid >> 3;          // staging c (0..63)
    int p4 = tid & 7;            // staging px4 (0..7)
    f4 acc[4][2];
#pragma unroll
    for (int mt = 0; mt < 4; mt++) {
        f4 bias = *(const f4*)(shb + mt * 16 + lg * 4);
        acc[mt][0] = bias;
        acc[mt][1] = bias;
    }
    __syncthreads();
    for (int ch = 0; ch < 4; ch++) {    // c-chunks of 64
        // ---- stage: all 8 t, this c-chunk, 32 px -> LDS transposed ----
#pragma unroll
        for (int tt = 0; tt < 8; tt++) {
            f4 xv = *(const f4*)(x + ((long)(b * 8 + tt) * Cc + ch * 64 + cst) * HW
                                 + px0 + p4 * 4);
            const float* gp = gl + tt * 32 + p4 * 4;
#pragma unroll
            for (int k = 0; k < 4; k++) {
                int p = p4 * 4 + k;
                xs[(tt * 32 + p) * 72 + (cst ^ (((p >> 3) & 7) * 8))] = f2bf(xv[k] * gp[k]);
            }
        }
        __syncthreads();
        // ---- GEMM accumulate over this chunk's 64 c ----
#pragma unroll
        for (int dt = 0; dt < 3; dt++) {
            int tp = t + dt - 1;
            if (tp >= 0 && tp < Tt) {
                const ushort_t* Ap = wpack + ((long)(dt * 8 + ch * 2)) * 2048 + l * 8;
#pragma unroll
                for (int kb = 0; kb < 2; kb++) {
                    short8 av[4];
#pragma unroll
                    for (int mt = 0; mt < 4; mt++)
                        av[mt] = *(const short8*)(Ap + kb * 2048 + mt * 512);
#pragma unroll
                    for (int nt = 0; nt < 2; nt++) {
                        int pxl = nt * 16 + lr;
                        short8 bv = *(const short8*)(&xs[(tp * 32 + pxl) * 72 +
                                        ((kb * 32 + lg * 8) ^ (((pxl >> 3) & 7) * 8))]);
#pragma unroll
                        for (int mt = 0; mt < 4; mt++)
                            acc[mt][nt] = __builtin_amdgcn_mfma_f32_16x16x32_bf16(
                                av[mt], bv, acc[mt][nt], 0, 0, 0);
                    }
                }
            }
        }
        __syncthreads();
    }
    // ---- epilogue: relu + bf16; trelu[bt][px][o], us4 over 4 consecutive o ----
#pragma unroll
    for (int nt = 0; nt < 2; nt++) {
#pragma unroll
        for (int mt = 0; mt < 4; mt++) {
            us4 st;
#pragma unroll
            for (int r = 0; r < 4; r++)
                st[r] = f2bf(fmaxf(acc[mt][nt][r], 0.f));
            *(us4*)(trelu + ((long)(b * 8 + t) * HW + px0 + nt * 16 + lr) * 64
                    + mt * 16 + lg * 4) = st;
        }
    }
}

// ---------------- K4M: MFMA expand GEMM + sigmoid + x_t + spatial-sum partials ----------------
// C[px, c] = sum_o trelu[bt][px][o] * we[c][o]   (A = trelu, B = wepack)
// C layout: col(N=c) = l&15, row(M=px) = (l>>4)*4+r -> lane holds 4 consecutive px
// grid (49, 64 bt, 2 c-halves), block (64,4): wave wv owns 64 px x 32 c (2 n-tiles).
__global__ __launch_bounds__(256) void k4m(
    const float* __restrict__ x, const float* __restrict__ gate,
    const ushort_t* __restrict__ trelu, const ushort_t* __restrict__ wepack,
    ushort_t* __restrict__ xt, float* __restrict__ vpart) {
    int l = threadIdx.x, wv = threadIdx.y;
    int bt = blockIdx.y, b = bt >> 3, t = bt & 7;
    int P0 = blockIdx.x * 64;
    int lr = l & 15, lg = l >> 4;
    int ntg0 = blockIdx.z * 8 + wv * 2;       // global c-tile base (2 tiles per wave)

    short8 bfr[2][2];                          // [kb][ni] held in regs
#pragma unroll
    for (int kb = 0; kb < 2; kb++)
#pragma unroll
        for (int ni = 0; ni < 2; ni++)
            bfr[kb][ni] = *(const short8*)(wepack + ((long)(kb * 16 + ntg0 + ni) * 64 + l) * 8);

    f4 acc[4][2];
#pragma unroll
    for (int mi = 0; mi < 4; mi++)
#pragma unroll
        for (int ni = 0; ni < 2; ni++) acc[mi][ni] = f4{0.f, 0.f, 0.f, 0.f};

    const ushort_t* Ab = trelu + ((long)bt * HW + P0 + lr) * 64;
#pragma unroll
    for (int mi = 0; mi < 4; mi++) {
#pragma unroll
        for (int kb = 0; kb < 2; kb++) {
            short8 av = *(const short8*)(Ab + (long)mi * 16 * 64 + kb * 32 + lg * 8);
#pragma unroll
            for (int ni = 0; ni < 2; ni++)
                acc[mi][ni] = __builtin_amdgcn_mfma_f32_16x16x32_bf16(av, bfr[kb][ni],
                                                                      acc[mi][ni], 0, 0, 0);
        }
    }

    float csum[2] = {0.f, 0.f};
#pragma unroll
    for (int mi = 0; mi < 4; mi++) {
        int pxb = P0 + mi * 16 + lg * 4;
        f4 gv = *(const f4*)(gate + (long)bt * HW + pxb);
#pragma unroll
        for (int ni = 0; ni < 2; ni++) {
            int c = (ntg0 + ni) * 16 + lr;
            f4 xv = *(const f4*)(x + ((long)bt * Cc + c) * HW + pxb);
            us4 st;
            float s = 0.f;
#pragma unroll
            for (int r = 0; r < 4; r++) {
                float attn = 1.f / (1.f + __expf(-acc[mi][ni][r]));
                float v = xv[r] * gv[r] * (1.f + attn);
                st[r] = f2bf(v);
                s += v;
            }
            *(us4*)(xt + ((long)(b * Cc + c) * Tt + t) * HW + pxb) = st;
            csum[ni] += s;
        }
    }

    // reduce over lg (lanes l, l+16, l+32, l+48 share the same c)
#pragma unroll
    for (int ni = 0; ni < 2; ni++) {
        float s = csum[ni];
        s += __shfl_xor(s, 16);
        s += __shfl_xor(s, 32);
        if (lg == 0) {
            int c = (ntg0 + ni) * 16 + lr;
            vpart[((long)(b * Cc + c) * Tt + t) * VP + blockIdx.x] = s;
        }
    }
}

// ---------------- K5: dynamic temporal kernel (fc1->relu->fc2->softmax) ----------------
__global__ __launch_bounds__(256) void k5_dyn(
    const float* __restrict__ vpart, const float* __restrict__ wfc1,
    const float* __restrict__ bfc1, const float* __restrict__ wfc2,
    const float* __restrict__ bfc2, float* __restrict__ dk) {
    int u = blockIdx.x * 256 + threadIdx.x;   // 2048 = B*C
    int b = u >> 8, c = u & 255;
    float v[8];
#pragma unroll
    for (int t = 0; t < 8; t++) {
        float s = 0.f;
        for (int i = 0; i < VP; i++)
            s += vpart[((long)(b * Cc + c) * Tt + t) * VP + i];
        v[t] = s * (1.f / 3136.f);
    }
    float h[16];
#pragma unroll
    for (int j = 0; j < 16; j++) {
        float s = bfc1[j];
        for (int t = 0; t < 8; t++) s += wfc1[j * 8 + t] * v[t];
        h[j] = fmaxf(s, 0.f);
    }
    float l[3];
#pragma unroll
    for (int k = 0; k < 3; k++) {
        float s = bfc2[k];
        for (int j = 0; j < 16; j++) s += wfc2[k * 16 + j] * h[j];
        l[k] = s;
    }
    float m = fmaxf(l[0], fmaxf(l[1], l[2]));
    float e0 = __expf(l[0] - m), e1 = __expf(l[1] - m), e2 = __expf(l[2] - m);
    float inv = 1.f / (e0 + e1 + e2);
    dk[(long)u * 3 + 0] = e0 * inv;
    dk[(long)u * 3 + 1] = e1 * inv;
    dk[(long)u * 3 + 2] = e2 * inv;
}

// ---------------- K6: depthwise temporal 3-tap stencil, 8 px/thread ----------------
// grid 3136, block 256: u over (b, c, px8). us8 loads, 2xf4 stores per t.
__global__ __launch_bounds__(256) void k6_stencil(
    const ushort_t* __restrict__ xt, const float* __restrict__ dk,
    float* __restrict__ out) {
    int u = blockIdx.x * 256 + threadIdx.x;    // 802816 = 8*256*392
    int px8 = u % 392, bc = u / 392;
    int px = px8 * 8;
    const float* kk = dk + (long)bc * 3;
    float k0 = kk[0], k1 = kk[1], k2 = kk[2];
    float pa[Tt][8];
    const ushort_t* src = xt + (long)bc * Tt * HW + px;
#pragma unroll
    for (int t = 0; t < Tt; t++) {
        us8 xv = *(const us8*)(src + (long)t * HW);
#pragma unroll
        for (int j = 0; j < 8; j++) pa[t][j] = bf2f(xv[j]);
    }
    int c = bc & 255, b = bc >> 8;
#pragma unroll
    for (int t = 0; t < Tt; t++) {
        f4 r0, r1;
#pragma unroll
        for (int j = 0; j < 4; j++) {
            float m = (t > 0) ? pa[t - 1][j] : 0.f;
            float p = (t < 7) ? pa[t + 1][j] : 0.f;
            r0[j] = k0 * m + k1 * pa[t][j] + k2 * p;
        }
#pragma unroll
        for (int j = 0; j < 4; j++) {
            float m = (t > 0) ? pa[t - 1][4 + j] : 0.f;
            float p = (t < 7) ? pa[t + 1][4 + j] : 0.f;
            r1[j] = k0 * m + k1 * pa[t][4 + j] + k2 * p;
        }
        float* op = out + ((long)(b * Tt + t) * Cc + c) * HW + px;
        *(f4*)(op) = r0;
        *(f4*)(op + 4) = r1;
    }
}

extern "C" void kernel_launch(void* const* d_in, const int* in_sizes, int n_in,
                              void* d_out, int out_size, void* d_ws, size_t ws_size,
                              hipStream_t stream) {
    const float* x    = (const float*)d_in[0];
    const float* wsp  = (const float*)d_in[1];
    const float* wr   = (const float*)d_in[2];
    const float* bng  = (const float*)d_in[3];
    const float* bnb  = (const float*)d_in[4];
    const float* bnm  = (const float*)d_in[5];
    const float* bnv  = (const float*)d_in[6];
    const float* we   = (const float*)d_in[7];
    const float* wfc1 = (const float*)d_in[8];
    const float* bfc1 = (const float*)d_in[9];
    const float* wfc2 = (const float*)d_in[10];
    const float* bfc2 = (const float*)d_in[11];
    float* out = (float*)d_out;

    char* ws = (char*)d_ws;
    size_t off = 0;
    ushort_t* trelu = (ushort_t*)(ws + off); off += (size_t)Bb * CH * Tt * HW * 2; // 25.7 MB
    // pooled partials (6.4 MB) alias trelu: dead after k2 reads them; k23 writes trelu after.
    float* pooledp = (float*)trelu;                                                // [4][64][2][HW]
    float* gate   = (float*)(ws + off); off += (size_t)64 * HW * 4;                // 0.8 MB
    ushort_t* xt  = (ushort_t*)(ws + off); off += (size_t)Bb * Cc * Tt * HW * 2;   // 102.8 MB
    float* vpart  = (float*)(ws + off); off += (size_t)Bb * Cc * Tt * VP * 4;      // 3.2 MB
    float* dk     = (float*)(ws + off); off += (size_t)Bb * Cc * 3 * 4;            // 24 KB
    ushort_t* wpack = (ushort_t*)(ws + off); off += (size_t)24 * 2048 * 2;         // 96 KB
    ushort_t* wepack = (ushort_t*)(ws + off); off += (size_t)2048 * 8 * 2;         // 32 KB
    float* shb    = (float*)(ws + off); off += (size_t)CH * 4;                     // 256 B

    hipLaunchKernelGGL(k0_pack, dim3(32), dim3(256), 0, stream,
                       wr, bng, bnb, bnm, bnv, we, wpack, wepack, shb);
    hipLaunchKernelGGL(k1_pool, dim3(196, 4), dim3(256), 0, stream, x, pooledp);
    hipLaunchKernelGGL(k2_conv, dim3(64), dim3(256), 0, stream, pooledp, wsp, gate);
    hipLaunchKernelGGL(k23_fused, dim3(98, 8), dim3(512), 37888, stream,
                       x, gate, wpack, shb, trelu);
    hipLaunchKernelGGL(k4m, dim3(49, 64, 2), dim3(64, 4), 0, stream,
                       x, gate, trelu, wepack, xt, vpart);
    hipLaunchKernelGGL(k5_dyn, dim3(8), dim3(256), 0, stream,
                       vpart, wfc1, bfc1, wfc2, bfc2, dk);
    hipLaunchKernelGGL(k6_stencil, dim3(3136), dim3(256), 0, stream, xt, dk, out);
}

// Round 4
// 609.439 us; speedup vs baseline: 2.3775x; 1.0881x over previous
//
#include <hip/hip_runtime.h>
#include <stdint.h>

#define HW 3136
#define Wd 56
#define Cc 256
#define CH 64
#define Tt 8
#define Bb 8
#define VP 49   // spatial-sum partials per (b,c,t): one per 64-px block of k4m

typedef unsigned short ushort_t;
typedef __attribute__((ext_vector_type(2))) unsigned short us2;
typedef __attribute__((ext_vector_type(4))) unsigned short us4;
typedef __attribute__((ext_vector_type(8))) unsigned short us8;
typedef __attribute__((ext_vector_type(8))) short short8;   // 8 bf16 (4 VGPRs) MFMA frag
typedef __attribute__((ext_vector_type(4))) float f4;
typedef __attribute__((ext_vector_type(2))) float f2;

__device__ __forceinline__ float bf2f(ushort_t u) {
    union { unsigned int i; float f; } v;
    v.i = ((unsigned int)u) << 16;
    return v.f;
}
__device__ __forceinline__ ushort_t f2bf(float f) {
    union { float f; unsigned int i; } v;
    v.f = f;
    unsigned int r = (v.i + 0x7FFFu + ((v.i >> 16) & 1u)) >> 16;
    return (ushort_t)r;
}

// ---------------- K0: pack weights into MFMA fragments (bf16) ----------------
// bx<24:  wpack[ks=dt*8+cb][mt][lane][8]: o = mt*16+(l&15), k(c) = cb*32+(l>>4)*8+j,
//         pre-scaled by BN inv[o]. Also shb[o] = bnb - bnm*inv (acc-init bias).
// bx>=24: wepack[kb][ntg][lane][8]: c = ntg*16+(l&15), k(o) = kb*32+(l>>4)*8+j.
__global__ __launch_bounds__(256) void k0_pack(
    const float* __restrict__ wr, const float* __restrict__ bng,
    const float* __restrict__ bnb, const float* __restrict__ bnm,
    const float* __restrict__ bnv, const float* __restrict__ we,
    ushort_t* __restrict__ wpack, ushort_t* __restrict__ wepack,
    float* __restrict__ shb) {
    int bx = blockIdx.x, tid = threadIdx.x;
    if (bx < 24) {
        int dt = bx >> 3, cb = bx & 7;
        int mt = tid >> 6, l = tid & 63;
        int o = mt * 16 + (l & 15);
        float inv = bng[o] * rsqrtf(bnv[o] + 1e-5f);
        int c0 = cb * 32 + (l >> 4) * 8;
        us8 v;
#pragma unroll
        for (int j = 0; j < 8; j++)
            v[j] = f2bf(wr[((long)o * Cc + c0 + j) * 3 + dt] * inv);
        *(us8*)(wpack + (long)bx * 2048 + (mt * 64 + l) * 8) = v;
        if (bx == 0 && tid < CH)
            shb[tid] = bnb[tid] - bnm[tid] * (bng[tid] * rsqrtf(bnv[tid] + 1e-5f));
    } else {
        int u = (bx - 24) * 256 + tid;          // 0..2047
        int l = u & 63;
        int c = ((u >> 6) & 15) * 16 + (l & 15);
        int o0 = (u >> 10) * 32 + (l >> 4) * 8;
        us8 v;
#pragma unroll
        for (int j = 0; j < 8; j++)
            v[j] = f2bf(we[(long)c * CH + o0 + j]);
        *(us8*)(wepack + (long)u * 8) = v;
    }
}

// ---------------- K1: channel max/mean pooling, 4-way c-split ----------------
// grid (196, 4), block 256. part q covers c in [q*64, q*64+64); partials combined in k2.
__global__ __launch_bounds__(256) void k1_pool(const float* __restrict__ x,
                                               float* __restrict__ pooledp) {
    int u = blockIdx.x * 256 + threadIdx.x;      // 50176 = 64 bt * 784 px4
    int q = blockIdx.y;
    int px4 = u % 784, bt = u / 784;
    long base = ((long)bt * Cc + (long)q * 64) * HW + px4 * 4;
    float mx[4], sm[4];
#pragma unroll
    for (int j = 0; j < 4; j++) { mx[j] = -3.4e38f; sm[j] = 0.f; }
    for (int c = 0; c < 64; c++) {
        f4 xv = *(const f4*)(x + base + (long)c * HW);
#pragma unroll
        for (int j = 0; j < 4; j++) {
            mx[j] = fmaxf(mx[j], xv[j]);
            sm[j] += xv[j];
        }
    }
    f4 pm, ps;
#pragma unroll
    for (int j = 0; j < 4; j++) { pm[j] = mx[j]; ps[j] = sm[j]; }
    *(f4*)(pooledp + ((long)(q * 64 + bt) * 2 + 0) * HW + px4 * 4) = pm;
    *(f4*)(pooledp + ((long)(q * 64 + bt) * 2 + 1) * HW + px4 * 4) = ps;
}

// ---------------- K2: combine partials + 7x7 2ch conv + sigmoid gate (row-tiled) ----------------
// grid (64 bt, 4 row-tiles), block 256. Each block: 14 output rows, 20 staged rows (3-row halo).
__global__ __launch_bounds__(256) void k2_conv(const float* __restrict__ pooledp,
                                               const float* __restrict__ wsp,
                                               float* __restrict__ gate) {
    __shared__ float img[2][20 * Wd];
    __shared__ float wf[98];
    int bt = blockIdx.x, rb = blockIdx.y, tid = threadIdx.x;
    int y0 = rb * 14;
    for (int i = tid; i < 20 * Wd; i += 256) {
        int ry = i / Wd, cx = i % Wd;
        int y = y0 - 3 + ry;
        float m = 0.f, s = 0.f;
        if (y >= 0 && y < Wd) {
            int p = y * Wd + cx;
            m = -3.4e38f;
#pragma unroll
            for (int q = 0; q < 4; q++) {
                const float* pq = pooledp + (long)(q * 64 + bt) * 2 * HW;
                m = fmaxf(m, pq[p]);
                s += pq[HW + p];
            }
            s *= (1.f / 256.f);
        }
        img[0][i] = m;
        img[1][i] = s;
    }
    if (tid < 98) wf[tid] = wsp[tid];
    __syncthreads();
    for (int p = tid; p < 14 * Wd; p += 256) {
        int ly = p / Wd, xx = p % Wd;
        int y = y0 + ly;
        float acc = 0.f;
        for (int ci = 0; ci < 2; ci++)
            for (int ky = 0; ky < 7; ky++) {
                int yy = y + ky - 3;
                if (yy < 0 || yy >= Wd) continue;
                int ri = yy - (y0 - 3);
                for (int kx = 0; kx < 7; kx++) {
                    int xc = xx + kx - 3;
                    if (xc < 0 || xc >= Wd) continue;
                    acc += wf[ci * 49 + ky * 7 + kx] * img[ci][ri * Wd + xc];
                }
            }
        gate[(long)bt * HW + y * Wd + xx] = 1.f + 1.f / (1.f + __expf(-acc));
    }
}

// ---------------- K23: fused gate-apply + LDS transpose + temporal-reduce MFMA GEMM ----------------
// Per (b, 32-px tile): stage bf16(x*gate) for all 8 t x 64c chunk into LDS (transposed,
// XOR-swizzled, double-buffered), each wave (= one t) accumulates C[o,px] over 3 taps via MFMA.
// trelu[bt][px][o] o-contiguous, BN folded (weights pre-scaled, bias in acc init) + relu.
// grid (98, 8 b), block 512 (8 waves), dynamic LDS 74752 B.
__global__ __launch_bounds__(512) void k23_fused(
    const float* __restrict__ x, const float* __restrict__ gate,
    const ushort_t* __restrict__ wpack, const float* __restrict__ shb,
    ushort_t* __restrict__ trelu) {
    extern __shared__ char smem[];
    ushort_t* xs0 = (ushort_t*)smem;                        // [256 rows][72]
    ushort_t* xs1 = xs0 + 256 * 72;
    float* gl = (float*)(smem + 2 * 256 * 72 * 2);          // [8t][32px]
    int tid = threadIdx.x;
    int px0 = blockIdx.x * 32, b = blockIdx.y;
    if (tid < 256) {
        int tg = tid >> 5, pg = tid & 31;
        gl[tid] = gate[(long)(b * 8 + tg) * HW + px0 + pg];
    }
    int t = tid >> 6;            // wave id = output t
    int l = tid & 63;
    int lr = l & 15, lg = l >> 4;
    int cst = tid >> 3;          // staging c (0..63)
    int p4 = tid & 7;            // staging px4 (0..7)
    f4 acc[4][2];
#pragma unroll
    for (int mt = 0; mt < 4; mt++) {
        f4 bias = *(const f4*)(shb + mt * 16 + lg * 4);
        acc[mt][0] = bias;
        acc[mt][1] = bias;
    }

    auto STAGE = [&](ushort_t* buf, int ch) {
#pragma unroll
        for (int tt = 0; tt < 8; tt++) {
            f4 xv = *(const f4*)(x + ((long)(b * 8 + tt) * Cc + ch * 64 + cst) * HW
                                 + px0 + p4 * 4);
            const float* gp = gl + tt * 32 + p4 * 4;
#pragma unroll
            for (int k = 0; k < 4; k++) {
                int p = p4 * 4 + k;
                buf[(tt * 32 + p) * 72 + (cst ^ (((p >> 3) & 7) * 8))] = f2bf(xv[k] * gp[k]);
            }
        }
    };

    __syncthreads();             // gl ready
    STAGE(xs0, 0);
    __syncthreads();
    for (int ch = 0; ch < 4; ch++) {
        ushort_t* cur = (ch & 1) ? xs1 : xs0;
        ushort_t* nxt = (ch & 1) ? xs0 : xs1;
        if (ch < 3) STAGE(nxt, ch + 1);
        // ---- GEMM accumulate over this chunk's 64 c ----
#pragma unroll
        for (int dt = 0; dt < 3; dt++) {
            int tp = t + dt - 1;
            if (tp >= 0 && tp < Tt) {
                const ushort_t* Ap = wpack + ((long)(dt * 8 + ch * 2)) * 2048 + l * 8;
#pragma unroll
                for (int kb = 0; kb < 2; kb++) {
                    short8 av[4];
#pragma unroll
                    for (int mt = 0; mt < 4; mt++)
                        av[mt] = *(const short8*)(Ap + kb * 2048 + mt * 512);
#pragma unroll
                    for (int nt = 0; nt < 2; nt++) {
                        int pxl = nt * 16 + lr;
                        short8 bv = *(const short8*)(&cur[(tp * 32 + pxl) * 72 +
                                        ((kb * 32 + lg * 8) ^ (((pxl >> 3) & 7) * 8))]);
#pragma unroll
                        for (int mt = 0; mt < 4; mt++)
                            acc[mt][nt] = __builtin_amdgcn_mfma_f32_16x16x32_bf16(
                                av[mt], bv, acc[mt][nt], 0, 0, 0);
                    }
                }
            }
        }
        __syncthreads();
    }
    // ---- epilogue: relu + bf16; trelu[bt][px][o], us4 over 4 consecutive o ----
#pragma unroll
    for (int nt = 0; nt < 2; nt++) {
#pragma unroll
        for (int mt = 0; mt < 4; mt++) {
            us4 st;
#pragma unroll
            for (int r = 0; r < 4; r++)
                st[r] = f2bf(fmaxf(acc[mt][nt][r], 0.f));
            *(us4*)(trelu + ((long)(b * 8 + t) * HW + px0 + nt * 16 + lr) * 64
                    + mt * 16 + lg * 4) = st;
        }
    }
}

// ---------------- K4M: MFMA expand GEMM + sigmoid + x_t + spatial-sum partials ----------------
// C[px, c] = sum_o trelu[bt][px][o] * we[c][o]   (A = trelu, B = wepack)
// C layout: col(N=c) = l&15, row(M=px) = (l>>4)*4+r -> lane holds 4 consecutive px
// grid (49, 64 bt), block (64,4): wave wv owns 64 px x 64 c (4 n-tiles).
__global__ __launch_bounds__(256) void k4m(
    const float* __restrict__ x, const float* __restrict__ gate,
    const ushort_t* __restrict__ trelu, const ushort_t* __restrict__ wepack,
    ushort_t* __restrict__ xt, float* __restrict__ vpart) {
    int l = threadIdx.x, wv = threadIdx.y;
    int bt = blockIdx.y, b = bt >> 3, t = bt & 7;
    int P0 = blockIdx.x * 64;
    int lr = l & 15, lg = l >> 4;
    int ntg0 = wv * 4;                         // global c-tile base (4 tiles per wave)

    short8 bfr[2][4];                          // [kb][ni] held in regs
#pragma unroll
    for (int kb = 0; kb < 2; kb++)
#pragma unroll
        for (int ni = 0; ni < 4; ni++)
            bfr[kb][ni] = *(const short8*)(wepack + ((long)(kb * 16 + ntg0 + ni) * 64 + l) * 8);

    f4 acc[4][4];
#pragma unroll
    for (int mi = 0; mi < 4; mi++)
#pragma unroll
        for (int ni = 0; ni < 4; ni++) acc[mi][ni] = f4{0.f, 0.f, 0.f, 0.f};

    const ushort_t* Ab = trelu + ((long)bt * HW + P0 + lr) * 64;
#pragma unroll
    for (int mi = 0; mi < 4; mi++) {
#pragma unroll
        for (int kb = 0; kb < 2; kb++) {
            short8 av = *(const short8*)(Ab + (long)mi * 16 * 64 + kb * 32 + lg * 8);
#pragma unroll
            for (int ni = 0; ni < 4; ni++)
                acc[mi][ni] = __builtin_amdgcn_mfma_f32_16x16x32_bf16(av, bfr[kb][ni],
                                                                      acc[mi][ni], 0, 0, 0);
        }
    }

    float csum[4] = {0.f, 0.f, 0.f, 0.f};
#pragma unroll
    for (int mi = 0; mi < 4; mi++) {
        int pxb = P0 + mi * 16 + lg * 4;
        f4 gv = *(const f4*)(gate + (long)bt * HW + pxb);
#pragma unroll
        for (int ni = 0; ni < 4; ni++) {
            int c = (ntg0 + ni) * 16 + lr;
            f4 xv = *(const f4*)(x + ((long)bt * Cc + c) * HW + pxb);
            us4 st;
            float s = 0.f;
#pragma unroll
            for (int r = 0; r < 4; r++) {
                float attn = 1.f / (1.f + __expf(-acc[mi][ni][r]));
                float v = xv[r] * gv[r] * (1.f + attn);
                st[r] = f2bf(v);
                s += v;
            }
            *(us4*)(xt + ((long)(b * Cc + c) * Tt + t) * HW + pxb) = st;
            csum[ni] += s;
        }
    }

    // reduce over lg (lanes l, l+16, l+32, l+48 share the same c)
#pragma unroll
    for (int ni = 0; ni < 4; ni++) {
        float s = csum[ni];
        s += __shfl_xor(s, 16);
        s += __shfl_xor(s, 32);
        if (lg == 0) {
            int c = (ntg0 + ni) * 16 + lr;
            vpart[((long)(b * Cc + c) * Tt + t) * VP + blockIdx.x] = s;
        }
    }
}

// ---------------- K5: dynamic temporal kernel (fc1->relu->fc2->softmax) ----------------
__global__ __launch_bounds__(256) void k5_dyn(
    const float* __restrict__ vpart, const float* __restrict__ wfc1,
    const float* __restrict__ bfc1, const float* __restrict__ wfc2,
    const float* __restrict__ bfc2, float* __restrict__ dk) {
    int u = blockIdx.x * 256 + threadIdx.x;   // 2048 = B*C
    int b = u >> 8, c = u & 255;
    float v[8];
#pragma unroll
    for (int t = 0; t < 8; t++) {
        float s = 0.f;
        for (int i = 0; i < VP; i++)
            s += vpart[((long)(b * Cc + c) * Tt + t) * VP + i];
        v[t] = s * (1.f / 3136.f);
    }
    float h[16];
#pragma unroll
    for (int j = 0; j < 16; j++) {
        float s = bfc1[j];
        for (int t = 0; t < 8; t++) s += wfc1[j * 8 + t] * v[t];
        h[j] = fmaxf(s, 0.f);
    }
    float l[3];
#pragma unroll
    for (int k = 0; k < 3; k++) {
        float s = bfc2[k];
        for (int j = 0; j < 16; j++) s += wfc2[k * 16 + j] * h[j];
        l[k] = s;
    }
    float m = fmaxf(l[0], fmaxf(l[1], l[2]));
    float e0 = __expf(l[0] - m), e1 = __expf(l[1] - m), e2 = __expf(l[2] - m);
    float inv = 1.f / (e0 + e1 + e2);
    dk[(long)u * 3 + 0] = e0 * inv;
    dk[(long)u * 3 + 1] = e1 * inv;
    dk[(long)u * 3 + 2] = e2 * inv;
}

// ---------------- K6: depthwise temporal 3-tap stencil, 8 px/thread ----------------
// grid 3136, block 256: u over (b, c, px8). us8 loads, 2xf4 stores per t.
__global__ __launch_bounds__(256) void k6_stencil(
    const ushort_t* __restrict__ xt, const float* __restrict__ dk,
    float* __restrict__ out) {
    int u = blockIdx.x * 256 + threadIdx.x;    // 802816 = 8*256*392
    int px8 = u % 392, bc = u / 392;
    int px = px8 * 8;
    const float* kk = dk + (long)bc * 3;
    float k0 = kk[0], k1 = kk[1], k2 = kk[2];
    float pa[Tt][8];
    const ushort_t* src = xt + (long)bc * Tt * HW + px;
#pragma unroll
    for (int t = 0; t < Tt; t++) {
        us8 xv = *(const us8*)(src + (long)t * HW);
#pragma unroll
        for (int j = 0; j < 8; j++) pa[t][j] = bf2f(xv[j]);
    }
    int c = bc & 255, b = bc >> 8;
#pragma unroll
    for (int t = 0; t < Tt; t++) {
        f4 r0, r1;
#pragma unroll
        for (int j = 0; j < 4; j++) {
            float m = (t > 0) ? pa[t - 1][j] : 0.f;
            float p = (t < 7) ? pa[t + 1][j] : 0.f;
            r0[j] = k0 * m + k1 * pa[t][j] + k2 * p;
        }
#pragma unroll
        for (int j = 0; j < 4; j++) {
            float m = (t > 0) ? pa[t - 1][4 + j] : 0.f;
            float p = (t < 7) ? pa[t + 1][4 + j] : 0.f;
            r1[j] = k0 * m + k1 * pa[t][4 + j] + k2 * p;
        }
        float* op = out + ((long)(b * Tt + t) * Cc + c) * HW + px;
        *(f4*)(op) = r0;
        *(f4*)(op + 4) = r1;
    }
}

extern "C" void kernel_launch(void* const* d_in, const int* in_sizes, int n_in,
                              void* d_out, int out_size, void* d_ws, size_t ws_size,
                              hipStream_t stream) {
    const float* x    = (const float*)d_in[0];
    const float* wsp  = (const float*)d_in[1];
    const float* wr   = (const float*)d_in[2];
    const float* bng  = (const float*)d_in[3];
    const float* bnb  = (const float*)d_in[4];
    const float* bnm  = (const float*)d_in[5];
    const float* bnv  = (const float*)d_in[6];
    const float* we   = (const float*)d_in[7];
    const float* wfc1 = (const float*)d_in[8];
    const float* bfc1 = (const float*)d_in[9];
    const float* wfc2 = (const float*)d_in[10];
    const float* bfc2 = (const float*)d_in[11];
    float* out = (float*)d_out;

    char* ws = (char*)d_ws;
    size_t off = 0;
    ushort_t* trelu = (ushort_t*)(ws + off); off += (size_t)Bb * CH * Tt * HW * 2; // 25.7 MB
    // pooled partials (6.4 MB) alias trelu: dead after k2 reads them; k23 writes trelu after.
    float* pooledp = (float*)trelu;                                                // [4][64][2][HW]
    float* gate   = (float*)(ws + off); off += (size_t)64 * HW * 4;                // 0.8 MB
    ushort_t* xt  = (ushort_t*)(ws + off); off += (size_t)Bb * Cc * Tt * HW * 2;   // 102.8 MB
    float* vpart  = (float*)(ws + off); off += (size_t)Bb * Cc * Tt * VP * 4;      // 3.2 MB
    float* dk     = (float*)(ws + off); off += (size_t)Bb * Cc * 3 * 4;            // 24 KB
    ushort_t* wpack = (ushort_t*)(ws + off); off += (size_t)24 * 2048 * 2;         // 96 KB
    ushort_t* wepack = (ushort_t*)(ws + off); off += (size_t)2048 * 8 * 2;         // 32 KB
    float* shb    = (float*)(ws + off); off += (size_t)CH * 4;                     // 256 B

    hipLaunchKernelGGL(k0_pack, dim3(32), dim3(256), 0, stream,
                       wr, bng, bnb, bnm, bnv, we, wpack, wepack, shb);
    hipLaunchKernelGGL(k1_pool, dim3(196, 4), dim3(256), 0, stream, x, pooledp);
    hipLaunchKernelGGL(k2_conv, dim3(64, 4), dim3(256), 0, stream, pooledp, wsp, gate);
    hipLaunchKernelGGL(k23_fused, dim3(98, 8), dim3(512), 74752, stream,
                       x, gate, wpack, shb, trelu);
    hipLaunchKernelGGL(k4m, dim3(49, 64), dim3(64, 4), 0, stream,
                       x, gate, trelu, wepack, xt, vpart);
    hipLaunchKernelGGL(k5_dyn, dim3(8), dim3(256), 0, stream,
                       vpart, wfc1, bfc1, wfc2, bfc2, dk);
    hipLaunchKernelGGL(k6_stencil, dim3(3136), dim3(256), 0, stream, xt, dk, out);
}

// Round 5
// 604.802 us; speedup vs baseline: 2.3957x; 1.0077x over previous
//
#include <hip/hip_runtime.h>
#include <stdint.h>

#define HW 3136
#define Wd 56
#define Cc 256
#define CH 64
#define Tt 8
#define Bb 8
#define VP 49   // spatial-sum partials per (b,c,t): one per 64-px block of k4m

typedef unsigned short ushort_t;
typedef __attribute__((ext_vector_type(2))) unsigned short us2;
typedef __attribute__((ext_vector_type(4))) unsigned short us4;
typedef __attribute__((ext_vector_type(8))) unsigned short us8;
typedef __attribute__((ext_vector_type(8))) short short8;   // 8 bf16 (4 VGPRs) MFMA frag
typedef __attribute__((ext_vector_type(4))) float f4;
typedef __attribute__((ext_vector_type(2))) float f2;

__device__ __forceinline__ float bf2f(ushort_t u) {
    union { unsigned int i; float f; } v;
    v.i = ((unsigned int)u) << 16;
    return v.f;
}
__device__ __forceinline__ ushort_t f2bf(float f) {
    union { float f; unsigned int i; } v;
    v.f = f;
    unsigned int r = (v.i + 0x7FFFu + ((v.i >> 16) & 1u)) >> 16;
    return (ushort_t)r;
}

// ---------------- K0: pack weights into MFMA fragments (bf16) ----------------
// bx<24:  wpack[ks=dt*8+cb][mt][lane][8]: o = mt*16+(l&15), k(c) = cb*32+(l>>4)*8+j,
//         pre-scaled by BN inv[o]. Also shb[o] = bnb - bnm*inv (acc-init bias).
// bx>=24: wepack[kb][ntg][lane][8]: c = ntg*16+(l&15), k(o) = kb*32+(l>>4)*8+j.
__global__ __launch_bounds__(256) void k0_pack(
    const float* __restrict__ wr, const float* __restrict__ bng,
    const float* __restrict__ bnb, const float* __restrict__ bnm,
    const float* __restrict__ bnv, const float* __restrict__ we,
    ushort_t* __restrict__ wpack, ushort_t* __restrict__ wepack,
    float* __restrict__ shb) {
    int bx = blockIdx.x, tid = threadIdx.x;
    if (bx < 24) {
        int dt = bx >> 3, cb = bx & 7;
        int mt = tid >> 6, l = tid & 63;
        int o = mt * 16 + (l & 15);
        float inv = bng[o] * rsqrtf(bnv[o] + 1e-5f);
        int c0 = cb * 32 + (l >> 4) * 8;
        us8 v;
#pragma unroll
        for (int j = 0; j < 8; j++)
            v[j] = f2bf(wr[((long)o * Cc + c0 + j) * 3 + dt] * inv);
        *(us8*)(wpack + (long)bx * 2048 + (mt * 64 + l) * 8) = v;
        if (bx == 0 && tid < CH)
            shb[tid] = bnb[tid] - bnm[tid] * (bng[tid] * rsqrtf(bnv[tid] + 1e-5f));
    } else {
        int u = (bx - 24) * 256 + tid;          // 0..2047
        int l = u & 63;
        int c = ((u >> 6) & 15) * 16 + (l & 15);
        int o0 = (u >> 10) * 32 + (l >> 4) * 8;
        us8 v;
#pragma unroll
        for (int j = 0; j < 8; j++)
            v[j] = f2bf(we[(long)c * CH + o0 + j]);
        *(us8*)(wepack + (long)u * 8) = v;
    }
}

// ---------------- K1: channel max/mean pooling, 4-way c-split ----------------
// grid (196, 4), block 256. part q covers c in [q*64, q*64+64); partials combined in k2.
__global__ __launch_bounds__(256) void k1_pool(const float* __restrict__ x,
                                               float* __restrict__ pooledp) {
    int u = blockIdx.x * 256 + threadIdx.x;      // 50176 = 64 bt * 784 px4
    int q = blockIdx.y;
    int px4 = u % 784, bt = u / 784;
    long base = ((long)bt * Cc + (long)q * 64) * HW + px4 * 4;
    float mx[4], sm[4];
#pragma unroll
    for (int j = 0; j < 4; j++) { mx[j] = -3.4e38f; sm[j] = 0.f; }
#pragma unroll 8
    for (int c = 0; c < 64; c++) {
        f4 xv = *(const f4*)(x + base + (long)c * HW);
#pragma unroll
        for (int j = 0; j < 4; j++) {
            mx[j] = fmaxf(mx[j], xv[j]);
            sm[j] += xv[j];
        }
    }
    f4 pm, ps;
#pragma unroll
    for (int j = 0; j < 4; j++) { pm[j] = mx[j]; ps[j] = sm[j]; }
    *(f4*)(pooledp + ((long)(q * 64 + bt) * 2 + 0) * HW + px4 * 4) = pm;
    *(f4*)(pooledp + ((long)(q * 64 + bt) * 2 + 1) * HW + px4 * 4) = ps;
}

// ---------------- K2: combine partials + 7x7 2ch conv + sigmoid gate (row-tiled) ----------------
// grid (64 bt, 4 row-tiles), block 256. Each block: 14 output rows, 20 staged rows (3-row halo).
__global__ __launch_bounds__(256) void k2_conv(const float* __restrict__ pooledp,
                                               const float* __restrict__ wsp,
                                               float* __restrict__ gate) {
    __shared__ float img[2][20 * Wd];
    __shared__ float wf[98];
    int bt = blockIdx.x, rb = blockIdx.y, tid = threadIdx.x;
    int y0 = rb * 14;
    for (int i = tid; i < 20 * Wd; i += 256) {
        int ry = i / Wd, cx = i % Wd;
        int y = y0 - 3 + ry;
        float m = 0.f, s = 0.f;
        if (y >= 0 && y < Wd) {
            int p = y * Wd + cx;
            m = -3.4e38f;
#pragma unroll
            for (int q = 0; q < 4; q++) {
                const float* pq = pooledp + (long)(q * 64 + bt) * 2 * HW;
                m = fmaxf(m, pq[p]);
                s += pq[HW + p];
            }
            s *= (1.f / 256.f);
        }
        img[0][i] = m;
        img[1][i] = s;
    }
    if (tid < 98) wf[tid] = wsp[tid];
    __syncthreads();
    for (int p = tid; p < 14 * Wd; p += 256) {
        int ly = p / Wd, xx = p % Wd;
        int y = y0 + ly;
        float acc = 0.f;
        for (int ci = 0; ci < 2; ci++)
            for (int ky = 0; ky < 7; ky++) {
                int yy = y + ky - 3;
                if (yy < 0 || yy >= Wd) continue;
                int ri = yy - (y0 - 3);
                for (int kx = 0; kx < 7; kx++) {
                    int xc = xx + kx - 3;
                    if (xc < 0 || xc >= Wd) continue;
                    acc += wf[ci * 49 + ky * 7 + kx] * img[ci][ri * Wd + xc];
                }
            }
        gate[(long)bt * HW + y * Wd + xx] = 1.f + 1.f / (1.f + __expf(-acc));
    }
}

// ---------------- K23: fused gate-apply + LDS transpose + temporal-reduce MFMA GEMM ----------------
// Per (b, 32-px tile): stage bf16(x*gate) for all 8 t x 64c chunk into LDS (transposed,
// XOR-swizzled, double-buffered, us4-vectorized writes), each wave (= one t) accumulates
// C[o,px] over 3 taps via MFMA. trelu[bt][px][o] o-contiguous, BN folded + relu.
// grid (98, 8 b), block 512 (8 waves), dynamic LDS 74752 B.
__global__ __launch_bounds__(512) void k23_fused(
    const float* __restrict__ x, const float* __restrict__ gate,
    const ushort_t* __restrict__ wpack, const float* __restrict__ shb,
    ushort_t* __restrict__ trelu) {
    extern __shared__ char smem[];
    ushort_t* xs0 = (ushort_t*)smem;                        // [256 rows][72]
    ushort_t* xs1 = xs0 + 256 * 72;
    float* gl = (float*)(smem + 2 * 256 * 72 * 2);          // [8t][32px]
    int tid = threadIdx.x;
    int px0 = blockIdx.x * 32, b = blockIdx.y;
    if (tid < 256) {
        int tg = tid >> 5, pg = tid & 31;
        gl[tid] = gate[(long)(b * 8 + tg) * HW + px0 + pg];
    }
    int t = tid >> 6;            // wave id = output t
    int l = tid & 63;
    int lr = l & 15, lg = l >> 4;
    // staging decomposition: 4c x 4px x 2tt per thread
    int spg = tid & 7;           // px4 group (px = spg*4 .. +3)
    int scg = (tid >> 3) & 15;   // c group (c = scg*4 .. +3)
    int stp = tid >> 7;          // tt pair (tt = stp*2, stp*2+1)
    f4 acc[4][2];
#pragma unroll
    for (int mt = 0; mt < 4; mt++) {
        f4 bias = *(const f4*)(shb + mt * 16 + lg * 4);
        acc[mt][0] = bias;
        acc[mt][1] = bias;
    }

    auto STAGE = [&](ushort_t* buf, int ch) {
#pragma unroll
        for (int ti = 0; ti < 2; ti++) {
            int tt = stp * 2 + ti;
            f4 xv[4];
#pragma unroll
            for (int cc = 0; cc < 4; cc++)
                xv[cc] = *(const f4*)(x + ((long)(b * 8 + tt) * Cc + ch * 64 + scg * 4 + cc) * HW
                                      + px0 + spg * 4);
            const float* gp = gl + tt * 32 + spg * 4;
#pragma unroll
            for (int k = 0; k < 4; k++) {
                int p = spg * 4 + k;
                us4 w;
#pragma unroll
                for (int cc = 0; cc < 4; cc++) w[cc] = f2bf(xv[cc][k] * gp[k]);
                *(us4*)(&buf[(tt * 32 + p) * 72 + ((scg * 4) ^ (((p >> 3) & 7) * 8))]) = w;
            }
        }
    };

    __syncthreads();             // gl ready
    STAGE(xs0, 0);
    __syncthreads();
    for (int ch = 0; ch < 4; ch++) {
        ushort_t* cur = (ch & 1) ? xs1 : xs0;
        ushort_t* nxt = (ch & 1) ? xs0 : xs1;
        if (ch < 3) STAGE(nxt, ch + 1);
        // ---- GEMM accumulate over this chunk's 64 c ----
#pragma unroll
        for (int dt = 0; dt < 3; dt++) {
            int tp = t + dt - 1;
            if (tp >= 0 && tp < Tt) {
                const ushort_t* Ap = wpack + ((long)(dt * 8 + ch * 2)) * 2048 + l * 8;
#pragma unroll
                for (int kb = 0; kb < 2; kb++) {
                    short8 av[4];
#pragma unroll
                    for (int mt = 0; mt < 4; mt++)
                        av[mt] = *(const short8*)(Ap + kb * 2048 + mt * 512);
#pragma unroll
                    for (int nt = 0; nt < 2; nt++) {
                        int pxl = nt * 16 + lr;
                        short8 bv = *(const short8*)(&cur[(tp * 32 + pxl) * 72 +
                                        ((kb * 32 + lg * 8) ^ (((pxl >> 3) & 7) * 8))]);
#pragma unroll
                        for (int mt = 0; mt < 4; mt++)
                            acc[mt][nt] = __builtin_amdgcn_mfma_f32_16x16x32_bf16(
                                av[mt], bv, acc[mt][nt], 0, 0, 0);
                    }
                }
            }
        }
        __syncthreads();
    }
    // ---- epilogue: relu + bf16; trelu[bt][px][o], us4 over 4 consecutive o ----
#pragma unroll
    for (int nt = 0; nt < 2; nt++) {
#pragma unroll
        for (int mt = 0; mt < 4; mt++) {
            us4 st;
#pragma unroll
            for (int r = 0; r < 4; r++)
                st[r] = f2bf(fmaxf(acc[mt][nt][r], 0.f));
            *(us4*)(trelu + ((long)(b * 8 + t) * HW + px0 + nt * 16 + lr) * 64
                    + mt * 16 + lg * 4) = st;
        }
    }
}

// ---------------- K4M: MFMA expand GEMM + sigmoid + x_t + spatial-sum partials ----------------
// C[px, c] = sum_o trelu[bt][px][o] * we[c][o]   (A = trelu, B = wepack)
// C layout: col(N=c) = l&15, row(M=px) = (l>>4)*4+r -> lane holds 4 consecutive px
// grid (49, 64 bt), block (64,4): wave wv owns 64 px x 64 c (4 n-tiles).
// x/gate HBM loads issued at kernel entry so their latency hides under the GEMM (T14).
__global__ __launch_bounds__(256) void k4m(
    const float* __restrict__ x, const float* __restrict__ gate,
    const ushort_t* __restrict__ trelu, const ushort_t* __restrict__ wepack,
    ushort_t* __restrict__ xt, float* __restrict__ vpart) {
    int l = threadIdx.x, wv = threadIdx.y;
    int bt = blockIdx.y, b = bt >> 3, t = bt & 7;
    int P0 = blockIdx.x * 64;
    int lr = l & 15, lg = l >> 4;
    int ntg0 = wv * 4;                         // global c-tile base (4 tiles per wave)

    // ---- prefetch: all epilogue x / gate loads issued first ----
    f4 gv[4], xv[4][4];
#pragma unroll
    for (int mi = 0; mi < 4; mi++) {
        int pxb = P0 + mi * 16 + lg * 4;
        gv[mi] = *(const f4*)(gate + (long)bt * HW + pxb);
#pragma unroll
        for (int ni = 0; ni < 4; ni++) {
            int c = (ntg0 + ni) * 16 + lr;
            xv[mi][ni] = *(const f4*)(x + ((long)bt * Cc + c) * HW + pxb);
        }
    }

    short8 bfr[2][4];                          // [kb][ni] held in regs
#pragma unroll
    for (int kb = 0; kb < 2; kb++)
#pragma unroll
        for (int ni = 0; ni < 4; ni++)
            bfr[kb][ni] = *(const short8*)(wepack + ((long)(kb * 16 + ntg0 + ni) * 64 + l) * 8);

    f4 acc[4][4];
#pragma unroll
    for (int mi = 0; mi < 4; mi++)
#pragma unroll
        for (int ni = 0; ni < 4; ni++) acc[mi][ni] = f4{0.f, 0.f, 0.f, 0.f};

    const ushort_t* Ab = trelu + ((long)bt * HW + P0 + lr) * 64;
#pragma unroll
    for (int mi = 0; mi < 4; mi++) {
#pragma unroll
        for (int kb = 0; kb < 2; kb++) {
            short8 av = *(const short8*)(Ab + (long)mi * 16 * 64 + kb * 32 + lg * 8);
#pragma unroll
            for (int ni = 0; ni < 4; ni++)
                acc[mi][ni] = __builtin_amdgcn_mfma_f32_16x16x32_bf16(av, bfr[kb][ni],
                                                                      acc[mi][ni], 0, 0, 0);
        }
    }

    float csum[4] = {0.f, 0.f, 0.f, 0.f};
#pragma unroll
    for (int mi = 0; mi < 4; mi++) {
        int pxb = P0 + mi * 16 + lg * 4;
#pragma unroll
        for (int ni = 0; ni < 4; ni++) {
            int c = (ntg0 + ni) * 16 + lr;
            us4 st;
            float s = 0.f;
#pragma unroll
            for (int r = 0; r < 4; r++) {
                float attn = 1.f / (1.f + __expf(-acc[mi][ni][r]));
                float v = xv[mi][ni][r] * gv[mi][r] * (1.f + attn);
                st[r] = f2bf(v);
                s += v;
            }
            *(us4*)(xt + ((long)(b * Cc + c) * Tt + t) * HW + pxb) = st;
            csum[ni] += s;
        }
    }

    // reduce over lg (lanes l, l+16, l+32, l+48 share the same c)
#pragma unroll
    for (int ni = 0; ni < 4; ni++) {
        float s = csum[ni];
        s += __shfl_xor(s, 16);
        s += __shfl_xor(s, 32);
        if (lg == 0) {
            int c = (ntg0 + ni) * 16 + lr;
            vpart[((long)(b * Cc + c) * Tt + t) * VP + blockIdx.x] = s;
        }
    }
}

// ---------------- K5: dynamic temporal kernel (fc1->relu->fc2->softmax) ----------------
__global__ __launch_bounds__(256) void k5_dyn(
    const float* __restrict__ vpart, const float* __restrict__ wfc1,
    const float* __restrict__ bfc1, const float* __restrict__ wfc2,
    const float* __restrict__ bfc2, float* __restrict__ dk) {
    int u = blockIdx.x * 256 + threadIdx.x;   // 2048 = B*C
    int b = u >> 8, c = u & 255;
    float v[8];
#pragma unroll
    for (int t = 0; t < 8; t++) {
        float s = 0.f;
        for (int i = 0; i < VP; i++)
            s += vpart[((long)(b * Cc + c) * Tt + t) * VP + i];
        v[t] = s * (1.f / 3136.f);
    }
    float h[16];
#pragma unroll
    for (int j = 0; j < 16; j++) {
        float s = bfc1[j];
        for (int t = 0; t < 8; t++) s += wfc1[j * 8 + t] * v[t];
        h[j] = fmaxf(s, 0.f);
    }
    float l[3];
#pragma unroll
    for (int k = 0; k < 3; k++) {
        float s = bfc2[k];
        for (int j = 0; j < 16; j++) s += wfc2[k * 16 + j] * h[j];
        l[k] = s;
    }
    float m = fmaxf(l[0], fmaxf(l[1], l[2]));
    float e0 = __expf(l[0] - m), e1 = __expf(l[1] - m), e2 = __expf(l[2] - m);
    float inv = 1.f / (e0 + e1 + e2);
    dk[(long)u * 3 + 0] = e0 * inv;
    dk[(long)u * 3 + 1] = e1 * inv;
    dk[(long)u * 3 + 2] = e2 * inv;
}

// ---------------- K6: depthwise temporal 3-tap stencil, 8 px/thread ----------------
// grid 3136, block 256: u over (b, c, px8). us8 loads, 2xf4 stores per t.
__global__ __launch_bounds__(256) void k6_stencil(
    const ushort_t* __restrict__ xt, const float* __restrict__ dk,
    float* __restrict__ out) {
    int u = blockIdx.x * 256 + threadIdx.x;    // 802816 = 8*256*392
    int px8 = u % 392, bc = u / 392;
    int px = px8 * 8;
    const float* kk = dk + (long)bc * 3;
    float k0 = kk[0], k1 = kk[1], k2 = kk[2];
    float pa[Tt][8];
    const ushort_t* src = xt + (long)bc * Tt * HW + px;
#pragma unroll
    for (int t = 0; t < Tt; t++) {
        us8 xv = *(const us8*)(src + (long)t * HW);
#pragma unroll
        for (int j = 0; j < 8; j++) pa[t][j] = bf2f(xv[j]);
    }
    int c = bc & 255, b = bc >> 8;
#pragma unroll
    for (int t = 0; t < Tt; t++) {
        f4 r0, r1;
#pragma unroll
        for (int j = 0; j < 4; j++) {
            float m = (t > 0) ? pa[t - 1][j] : 0.f;
            float p = (t < 7) ? pa[t + 1][j] : 0.f;
            r0[j] = k0 * m + k1 * pa[t][j] + k2 * p;
        }
#pragma unroll
        for (int j = 0; j < 4; j++) {
            float m = (t > 0) ? pa[t - 1][4 + j] : 0.f;
            float p = (t < 7) ? pa[t + 1][4 + j] : 0.f;
            r1[j] = k0 * m + k1 * pa[t][4 + j] + k2 * p;
        }
        float* op = out + ((long)(b * Tt + t) * Cc + c) * HW + px;
        *(f4*)(op) = r0;
        *(f4*)(op + 4) = r1;
    }
}

extern "C" void kernel_launch(void* const* d_in, const int* in_sizes, int n_in,
                              void* d_out, int out_size, void* d_ws, size_t ws_size,
                              hipStream_t stream) {
    const float* x    = (const float*)d_in[0];
    const float* wsp  = (const float*)d_in[1];
    const float* wr   = (const float*)d_in[2];
    const float* bng  = (const float*)d_in[3];
    const float* bnb  = (const float*)d_in[4];
    const float* bnm  = (const float*)d_in[5];
    const float* bnv  = (const float*)d_in[6];
    const float* we   = (const float*)d_in[7];
    const float* wfc1 = (const float*)d_in[8];
    const float* bfc1 = (const float*)d_in[9];
    const float* wfc2 = (const float*)d_in[10];
    const float* bfc2 = (const float*)d_in[11];
    float* out = (float*)d_out;

    char* ws = (char*)d_ws;
    size_t off = 0;
    ushort_t* trelu = (ushort_t*)(ws + off); off += (size_t)Bb * CH * Tt * HW * 2; // 25.7 MB
    // pooled partials (6.4 MB) alias trelu: dead after k2 reads them; k23 writes trelu after.
    float* pooledp = (float*)trelu;                                                // [4][64][2][HW]
    float* gate   = (float*)(ws + off); off += (size_t)64 * HW * 4;                // 0.8 MB
    ushort_t* xt  = (ushort_t*)(ws + off); off += (size_t)Bb * Cc * Tt * HW * 2;   // 102.8 MB
    float* vpart  = (float*)(ws + off); off += (size_t)Bb * Cc * Tt * VP * 4;      // 3.2 MB
    float* dk     = (float*)(ws + off); off += (size_t)Bb * Cc * 3 * 4;            // 24 KB
    ushort_t* wpack = (ushort_t*)(ws + off); off += (size_t)24 * 2048 * 2;         // 96 KB
    ushort_t* wepack = (ushort_t*)(ws + off); off += (size_t)2048 * 8 * 2;         // 32 KB
    float* shb    = (float*)(ws + off); off += (size_t)CH * 4;                     // 256 B

    hipLaunchKernelGGL(k0_pack, dim3(32), dim3(256), 0, stream,
                       wr, bng, bnb, bnm, bnv, we, wpack, wepack, shb);
    hipLaunchKernelGGL(k1_pool, dim3(196, 4), dim3(256), 0, stream, x, pooledp);
    hipLaunchKernelGGL(k2_conv, dim3(64, 4), dim3(256), 0, stream, pooledp, wsp, gate);
    hipLaunchKernelGGL(k23_fused, dim3(98, 8), dim3(512), 74752, stream,
                       x, gate, wpack, shb, trelu);
    hipLaunchKernelGGL(k4m, dim3(49, 64), dim3(64, 4), 0, stream,
                       x, gate, trelu, wepack, xt, vpart);
    hipLaunchKernelGGL(k5_dyn, dim3(8), dim3(256), 0, stream,
                       vpart, wfc1, bfc1, wfc2, bfc2, dk);
    hipLaunchKernelGGL(k6_stencil, dim3(3136), dim3(256), 0, stream, xt, dk, out);
}